// Round 1
// baseline (790.502 us; speedup 1.0000x reference)
//
#include <hip/hip_runtime.h>
#include <math.h>

#define H 1024
#define W 1024
#define HW (H * W)

typedef _Float16 half8 __attribute__((ext_vector_type(8)));
typedef _Float16 half4 __attribute__((ext_vector_type(4)));
typedef float f32x4 __attribute__((ext_vector_type(4)));

__device__ __forceinline__ float fast_sqrtf(float x) { return __builtin_amdgcn_sqrtf(x); }
__device__ __forceinline__ float fast_expf(float x) { return __builtin_amdgcn_exp2f(x * 1.44269504088896340736f); }

union U16 { unsigned short u; _Float16 f; };

__device__ __forceinline__ unsigned pack_hl(float v) {
    _Float16 h = (_Float16)v;
    _Float16 l = (_Float16)(v - (float)h);
    U16 a, b;
    a.f = h; b.f = l;
    return (unsigned)a.u | ((unsigned)b.u << 16);
}

// ---------------- stats pass 1: partial sum/sumsq per (b,c) chunk ----------------
__global__ __launch_bounds__(256) void stats_partial(const float* __restrict__ x,
                                                     double* __restrict__ part) {
    int blk = blockIdx.x;
    int bc = blk >> 5;
    int j = blk & 31;
    const float* p = x + (size_t)bc * HW + (size_t)j * (HW / 32);
    int tid = threadIdx.x;
    double s = 0.0, q = 0.0;
    const float4* p4 = (const float4*)p;
    for (int i = tid; i < (HW / 32) / 4; i += 256) {
        float4 v = p4[i];
        s += (double)v.x + (double)v.y + (double)v.z + (double)v.w;
        q += (double)v.x * v.x + (double)v.y * v.y + (double)v.z * v.z + (double)v.w * v.w;
    }
    __shared__ double ls[256], lq[256];
    ls[tid] = s;
    lq[tid] = q;
    __syncthreads();
    for (int ofs = 128; ofs > 0; ofs >>= 1) {
        if (tid < ofs) { ls[tid] += ls[tid + ofs]; lq[tid] += lq[tid + ofs]; }
        __syncthreads();
    }
    if (tid == 0) {
        part[blk * 2] = ls[0];
        part[blk * 2 + 1] = lq[0];
    }
}

// ---------------- stats pass 2 + weight prep ----------------
__global__ __launch_bounds__(256) void stats_final_prep(const double* __restrict__ part,
                                                        const float* __restrict__ chw,
                                                        const float* __restrict__ w1,
                                                        const float* __restrict__ w2,
                                                        const float* __restrict__ w3,
                                                        float* __restrict__ stats,
                                                        _Float16* __restrict__ w1a,
                                                        _Float16* __restrict__ w3f,
                                                        _Float16* __restrict__ w2bh,
                                                        _Float16* __restrict__ w2bl) {
    int tid = threadIdx.x;
    __shared__ float cw[4];
    if (tid == 0) {
        float m = fmaxf(fmaxf(chw[0], chw[1]), fmaxf(chw[2], chw[3]));
        float e0 = expf(chw[0] - m), e1 = expf(chw[1] - m);
        float e2 = expf(chw[2] - m), e3 = expf(chw[3] - m);
        float s = e0 + e1 + e2 + e3;
        cw[0] = e0 / s; cw[1] = e1 / s; cw[2] = e2 / s; cw[3] = e3 / s;
    }
    __syncthreads();
    if (tid < 16) {
        double s = 0.0, q = 0.0;
        for (int j = 0; j < 32; j++) {
            s += part[(tid * 32 + j) * 2];
            q += part[(tid * 32 + j) * 2 + 1];
        }
        double n = (double)HW;
        double var = (q - s * s / n) / (n - 1.0);
        if (var < 0) var = 0;
        float gs = (float)sqrt(var);
        int c = tid & 3;
        float gf = fminf(fmaxf(gs * 5.0f, 0.5f), 2.0f);
        float cf = fminf(fmaxf(gs * cw[c] * 2.0f, 0.8f), 1.2f);
        stats[tid * 2] = 0.05f * gf * cf;
        stats[tid * 2 + 1] = 0.20f * gf * cf;
    }
    for (int i = tid; i < 512; i += 256) {                 // conv1 A-frags
        int s = i >> 6, l = i & 63;
        int c = s >> 2, h = (s >> 1) & 1, hl = s & 1;
        int m = l & 15, cg = l >> 4;
        int co = h * 16 + m;
#pragma unroll
        for (int j = 0; j < 8; j++) {
            int k = c * 32 + cg * 8 + j;
            float v = 0.f;
            if (k < 36) {
                int t = k >> 2, ci = k & 3;
                v = w1[(co * 4 + ci) * 9 + t];
            }
            _Float16 hh = (_Float16)v;
            w1a[i * 8 + j] = hl ? (_Float16)(v - (float)hh) : hh;
        }
    }
    for (int idx = tid; idx < 576; idx += 256) {           // conv2 B-frags
        int t = idx >> 6, l = idx & 63;
        int co = l & 15, cg = l >> 4;
#pragma unroll
        for (int j = 0; j < 8; j++) {
            int ci = cg * 8 + j;
            float v = w2[(co * 32 + ci) * 9 + t];
            _Float16 hh = (_Float16)v;
            w2bh[idx * 8 + j] = hh;
            w2bl[idx * 8 + j] = (_Float16)(v - (float)hh);
        }
    }
    for (int idx = tid; idx < 768; idx += 256) {           // conv3 B-frags (12 sets x 64 lanes)
        int t = idx >> 6, l = idx & 63;
        int ky = t >> 2, grp = (t >> 1) & 1, hl = t & 1;
        int co = l & 15, bq = l >> 4;
#pragma unroll
        for (int j = 0; j < 8; j++) {
            int k = bq * 8 + j;
            float v = 0.f;
            if (co < 8) {
                if (grp == 0) {
                    int kxp = k >> 4, ci = k & 15;
                    v = w3[((co * 16 + ci) * 3 + ky) * 3 + kxp];
                } else if (k < 16) {
                    v = w3[((co * 16 + k) * 3 + ky) * 3 + 2];
                }
            }
            _Float16 hh = (_Float16)v;
            w3f[idx * 8 + j] = hl ? (_Float16)(v - (float)hh) : hh;
        }
    }
}

// ---------------- fused conv1+conv2+conv3, all via MFMA ----------------
// Output tile 30x8 of f3 (8 ch). f2 computed on 32x10 (zero waste), f1 on 34x12,
// x halo 36x14. f2 never leaves LDS -> kills the 64MB f2n HBM round trip + conv3 kernel.
__global__ __launch_bounds__(256, 2) void conv123_mfma(const float* __restrict__ x,
                                                       const _Float16* __restrict__ w1a,
                                                       const float* __restrict__ b1,
                                                       const _Float16* __restrict__ wbh,
                                                       const _Float16* __restrict__ wbl,
                                                       const float* __restrict__ b2,
                                                       const _Float16* __restrict__ w3f,
                                                       const float* __restrict__ b3,
                                                       float* __restrict__ f3) {
    // LDS map (60288 B total, lifetime-overlapped):
    //   f1t  : [0, 52224)      12 rows x 34 px x 128 B (swizzled f16 h/l, ch 0..31)
    //   xhl  : [52224, 60288)  4 ch x 14 rows x 36 cols packed f16 h|l (dead after conv1)
    //   tbuf : [0, 25600)      conv2 transpose scratch (overlays f1t after conv2 reads done)
    //   f2t  : [25600, 52800)  10 rows x 34 px x 80 B (conv3 input; overlays f1t tail/xhl head)
    __shared__ __align__(16) char smem[60288];
    char* f1t = smem;
    unsigned* xhl = (unsigned*)(smem + 52224);
    char* f2t = smem + 25600;
    int tid = threadIdx.x;
    int lane = tid & 63;
    int wid = tid >> 6;
    int bx = blockIdx.x * 30, by = blockIdx.y * 8;
    int n = lane & 15, cg = lane >> 4;

    // phase 0: stage x halo (rows by-3..by+10, cols bx-3..bx+32) as packed f16 h/l
    for (int idx = tid; idx < 2016; idx += 256) {
        int ci = idx / 504;
        int rem = idx - ci * 504;
        int r = rem / 36, c = rem - r * 36;
        int gy = by + r - 3, gx = bx + c - 3;
        float v = 0.f;
        if ((unsigned)gy < H && (unsigned)gx < W) v = x[ci * HW + gy * W + gx];
        xhl[idx] = pack_hl(v);
    }

    half8 Wf[8];
#pragma unroll
    for (int s = 0; s < 8; s++)
        Wf[s] = *(const half8*)(w1a + (s * 64 + lane) * 8);
    float bias1[8];
#pragma unroll
    for (int h = 0; h < 2; h++)
#pragma unroll
        for (int j = 0; j < 4; j++)
            bias1[h * 4 + j] = b1[h * 16 + cg * 4 + j];
    int t0 = 2 * cg, t1 = 2 * cg + 1;
    int dy0 = (t0 * 11) >> 5, dx0 = t0 - 3 * dy0;
    int dy1 = (t1 * 11) >> 5, dx1 = t1 - 3 * dy1;
    int off0 = dy0 * 36 + dx0, off1 = dy1 * 36 + dx1;
    __syncthreads();

    // phase 1: conv1 via MFMA; f1 on 34x12 = 408 px, 26 tiles of 16
#pragma unroll 1
    for (int tt = wid; tt < 26; tt += 4) {
        int p = tt * 16 + n;
        bool valid = p < 408;
        int pc = valid ? p : 407;
        int ry = pc / 34, cx = pc - ry * 34;
        int gy = by + ry - 2, gx = bx + cx - 2;
        bool ok = ((unsigned)gy < H) && ((unsigned)gx < W);
        int base = ry * 36 + cx;
        unsigned u0[8];
#pragma unroll
        for (int j = 0; j < 8; j++)
            u0[j] = xhl[(j & 3) * 504 + base + ((j < 4) ? off0 : off1)];
        half8 Xh0, Xl0;
#pragma unroll
        for (int j = 0; j < 8; j++) {
            U16 a; a.u = (unsigned short)u0[j]; Xh0[j] = a.f;
            U16 b; b.u = (unsigned short)(u0[j] >> 16); Xl0[j] = b.f;
        }
        half8 Xh1 = {0, 0, 0, 0, 0, 0, 0, 0}, Xl1 = {0, 0, 0, 0, 0, 0, 0, 0};
        if (cg == 0) {
#pragma unroll
            for (int j = 0; j < 4; j++) {
                unsigned v = xhl[j * 504 + base + 74];   // tap 8 (dy=2,dx=2)
                U16 a; a.u = (unsigned short)v; Xh1[j] = a.f;
                U16 b; b.u = (unsigned short)(v >> 16); Xl1[j] = b.f;
            }
        }
        f32x4 d0, d1;
#pragma unroll
        for (int j = 0; j < 4; j++) { d0[j] = bias1[j]; d1[j] = bias1[4 + j]; }
        d0 = __builtin_amdgcn_mfma_f32_16x16x32_f16(Wf[0], Xh0, d0, 0, 0, 0);
        d0 = __builtin_amdgcn_mfma_f32_16x16x32_f16(Wf[0], Xl0, d0, 0, 0, 0);
        d0 = __builtin_amdgcn_mfma_f32_16x16x32_f16(Wf[1], Xh0, d0, 0, 0, 0);
        d0 = __builtin_amdgcn_mfma_f32_16x16x32_f16(Wf[4], Xh1, d0, 0, 0, 0);
        d0 = __builtin_amdgcn_mfma_f32_16x16x32_f16(Wf[4], Xl1, d0, 0, 0, 0);
        d0 = __builtin_amdgcn_mfma_f32_16x16x32_f16(Wf[5], Xh1, d0, 0, 0, 0);
        d1 = __builtin_amdgcn_mfma_f32_16x16x32_f16(Wf[2], Xh0, d1, 0, 0, 0);
        d1 = __builtin_amdgcn_mfma_f32_16x16x32_f16(Wf[2], Xl0, d1, 0, 0, 0);
        d1 = __builtin_amdgcn_mfma_f32_16x16x32_f16(Wf[3], Xh0, d1, 0, 0, 0);
        d1 = __builtin_amdgcn_mfma_f32_16x16x32_f16(Wf[6], Xh1, d1, 0, 0, 0);
        d1 = __builtin_amdgcn_mfma_f32_16x16x32_f16(Wf[6], Xl1, d1, 0, 0, 0);
        d1 = __builtin_amdgcn_mfma_f32_16x16x32_f16(Wf[7], Xh1, d1, 0, 0, 0);
        if (valid) {
            int sw = (cx & 7) << 4;
            char* pxb = f1t + ry * 4352 + cx * 128;
#pragma unroll
            for (int h = 0; h < 2; h++) {
                f32x4 d = h ? d1 : d0;
                half4 hq, lq;
#pragma unroll
                for (int j = 0; j < 4; j++) {
                    float v = d[j];
                    v = v >= 0.f ? v : 0.2f * v;
                    v = ok ? v : 0.f;
                    _Float16 hv = (_Float16)v;
                    hq[j] = hv;
                    lq[j] = (_Float16)(v - (float)hv);
                }
                int q8 = (h * 4 + cg) * 8;
                *(half4*)(pxb + (q8 ^ sw)) = hq;
                *(half4*)(pxb + ((64 + q8) ^ sw)) = lq;
            }
        }
    }
    __syncthreads();

    // phase 2: conv2 via rolling-row f16x2 MFMA over f2 32x10 (wave = 16 cols x 5 rows)
    int m = lane & 15, b = lane >> 4;
    int wx = wid & 1, wy = wid >> 1;
    half8 Bh[9], Bl[9];
#pragma unroll
    for (int t = 0; t < 9; t++) {
        Bh[t] = *(const half8*)(wbh + (t * 64 + lane) * 8);
        Bl[t] = *(const half8*)(wbl + (t * 64 + lane) * 8);
    }
    float bc2 = b2[m];
    f32x4 acc2[5];
#pragma unroll
    for (int r = 0; r < 5; r++) acc2[r] = (f32x4){bc2, bc2, bc2, bc2};
#pragma unroll
    for (int iy = 0; iy < 7; iy++) {
        int f1row = wy * 5 + iy;
        half8 ah[3], al[3];
#pragma unroll
        for (int kx = 0; kx < 3; kx++) {
            int pxi = wx * 16 + m + kx;
            int base = f1row * 4352 + pxi * 128;
            int sw = (pxi & 7) << 4;
            ah[kx] = *(const half8*)(f1t + base + ((b * 16) ^ sw));
            al[kx] = *(const half8*)(f1t + base + ((64 + b * 16) ^ sw));
        }
#pragma unroll
        for (int kx = 0; kx < 3; kx++) {
#pragma unroll
            for (int ry = 0; ry < 5; ry++) {
                if (ry >= iy - 2 && ry <= iy) {
                    const int t = (iy - ry) * 3 + kx;
                    acc2[ry] = __builtin_amdgcn_mfma_f32_16x16x32_f16(ah[kx], Bh[t], acc2[ry], 0, 0, 0);
                    acc2[ry] = __builtin_amdgcn_mfma_f32_16x16x32_f16(ah[kx], Bl[t], acc2[ry], 0, 0, 0);
                    acc2[ry] = __builtin_amdgcn_mfma_f32_16x16x32_f16(al[kx], Bh[t], acc2[ry], 0, 0, 0);
                }
            }
        }
    }
    __syncthreads();   // all f1t reads done; f1t region becomes tbuf/f2t

    // conv2 epilogue: leaky -> LDS transpose -> f16 h/l into f2t (80 B px stride)
    float* tbuf = (float*)smem;
#pragma unroll
    for (int ry = 0; ry < 5; ry++) {
#pragma unroll
        for (int j = 0; j < 4; j++) {
            float v = acc2[ry][j];
            v = v >= 0.f ? v : 0.2f * v;
            tbuf[((wid * 5 + ry) * 16 + b * 4 + j) * 20 + m] = v;
        }
    }
    __syncthreads();
    {
        int px16 = lane & 15;
        int hco2 = (lane >> 4) & 1;
        int hl = lane >> 5;
#pragma unroll
        for (int ry = 0; ry < 5; ry++) {
            int row = wy * 5 + ry, col = wx * 16 + px16;
            int gy2 = by + row - 1, gx2 = bx + col - 1;
            bool okf = ((unsigned)gy2 < H) && ((unsigned)gx2 < W);
            const float4* src = (const float4*)&tbuf[((wid * 5 + ry) * 16 + px16) * 20 + hco2 * 8];
            float4 a4 = src[0], b4 = src[1];
            float vv[8] = {a4.x, a4.y, a4.z, a4.w, b4.x, b4.y, b4.z, b4.w};
            half8 o;
#pragma unroll
            for (int j = 0; j < 8; j++) {
                float v = okf ? vv[j] : 0.f;
                _Float16 hh = (_Float16)v;
                o[j] = hl ? (_Float16)(v - (float)hh) : hh;
            }
            *(half8*)(f2t + row * 2720 + col * 80 + hl * 32 + hco2 * 16) = o;
        }
        if (tid < 80) {   // zero pad cols 32,33 (read only by store-masked edge lanes)
            int rr = tid >> 3, c2 = 32 + ((tid >> 2) & 1), ch = tid & 3;
            half8 z = {0, 0, 0, 0, 0, 0, 0, 0};
            *(half8*)(f2t + rr * 2720 + c2 * 80 + ch * 16) = z;
        }
    }
    __syncthreads();

    // phase 3: conv3 from LDS f2t (identical structure to the old conv3_mfma)
    half8 F[12];
#pragma unroll
    for (int t = 0; t < 12; t++)
        F[t] = *(const half8*)(w3f + (t * 64 + lane) * 8);
    int hco = b & 1, kxp = b >> 1;
    float bc3 = (m < 8) ? b3[m] : 0.f;
    f32x4 acc[4];
#pragma unroll
    for (int r = 0; r < 4; r++) acc[r] = (f32x4){bc3, bc3, bc3, bc3};
    int pA = wx * 16 + m + kxp;                        // f2t px for A (kx -1,0)
    int pB = wx * 16 + m + 2;                          // f2t px for B (kx +1)
#pragma unroll
    for (int iy = 0; iy < 6; iy++) {
        const char* rp = f2t + (wy * 4 + iy) * 2720;
        half8 ka_h = *(const half8*)(rp + pA * 80 + hco * 16);
        half8 ka_l = *(const half8*)(rp + pA * 80 + hco * 16 + 32);
        half8 kb_h = *(const half8*)(rp + pB * 80 + hco * 16);
        half8 kb_l = *(const half8*)(rp + pB * 80 + hco * 16 + 32);
#pragma unroll
        for (int ry = 0; ry < 4; ry++) {
            if (ry >= iy - 2 && ry <= iy) {
                const int ky = iy - ry;
                acc[ry] = __builtin_amdgcn_mfma_f32_16x16x32_f16(ka_h, F[ky * 4 + 0], acc[ry], 0, 0, 0);
                acc[ry] = __builtin_amdgcn_mfma_f32_16x16x32_f16(ka_h, F[ky * 4 + 1], acc[ry], 0, 0, 0);
                acc[ry] = __builtin_amdgcn_mfma_f32_16x16x32_f16(ka_l, F[ky * 4 + 0], acc[ry], 0, 0, 0);
                acc[ry] = __builtin_amdgcn_mfma_f32_16x16x32_f16(kb_h, F[ky * 4 + 2], acc[ry], 0, 0, 0);
                acc[ry] = __builtin_amdgcn_mfma_f32_16x16x32_f16(kb_h, F[ky * 4 + 3], acc[ry], 0, 0, 0);
                acc[ry] = __builtin_amdgcn_mfma_f32_16x16x32_f16(kb_l, F[ky * 4 + 2], acc[ry], 0, 0, 0);
            }
        }
    }

    if (m < 8) {
        int ct = wx * 16 + b * 4;
        int gx0 = bx + ct;
        bool full = (ct + 3 < 30) && (gx0 + 3 < W);
#pragma unroll
        for (int ry = 0; ry < 4; ry++) {
            int y = by + wy * 4 + ry;
            float* dst = f3 + (size_t)m * HW + (size_t)y * W + gx0;
            if (full) {
                *(float4*)dst = make_float4(acc[ry][0], acc[ry][1], acc[ry][2], acc[ry][3]);
            } else {
#pragma unroll
                for (int j = 0; j < 4; j++)
                    if (ct + j < 30 && gx0 + j < W) dst[j] = acc[ry][j];
            }
        }
    }
}

// ---------------- stdfuse A: per-(tile,channel) partial std map ----------------
__global__ __launch_bounds__(256) void stdfuse_partial(const float* __restrict__ f3,
                                                       const float* __restrict__ fw,
                                                       float* __restrict__ pbuf) {
    __shared__ __align__(16) float raw[46 * 50];
    __shared__ __align__(16) float hsq[3][46 * 76];
    int tid = threadIdx.x;
    int xq = tid & 15, yp = tid >> 4;
    int bx = blockIdx.x * 32, by = blockIdx.y * 32;
    int z = blockIdx.z;
    const float* src = f3 + (size_t)z * HW;

    for (int idx = tid; idx < 2116; idx += 256) {
        int r = idx / 46, col = idx - r * 46;
        int gy = by + r - 7, gx = bx + col - 7;
        gy = gy < 0 ? -gy : (gy > 1023 ? 2046 - gy : gy);
        gx = gx < 0 ? -gx : (gx > 1023 ? 2046 - gx : gx);
        raw[r * 50 + col] = src[gy * W + gx];
    }
    __syncthreads();

    for (int idx = tid; idx < 736; idx += 256) {
        int r = idx >> 4, xh = idx & 15;
        const float* rp = raw + r * 50 + 2 * xh;
        float v[16], w[16];
#pragma unroll
        for (int k = 0; k < 8; k++) {
            float2 p = *(const float2*)(rp + 2 * k);
            v[2 * k] = p.x; v[2 * k + 1] = p.y;
        }
#pragma unroll
        for (int k = 0; k < 16; k++) w[k] = v[k] * v[k];
        float ms = v[6] + v[7] + v[8] + v[9];
        float mq = w[6] + w[7] + w[8] + w[9];
        float sA5 = v[5] + ms, sB5 = ms + v[10];
        float qA5 = w[5] + mq, qB5 = mq + w[10];
        float sA9 = sA5 + v[3] + v[4] + v[10] + v[11];
        float sB9 = sB5 + v[4] + v[5] + v[11] + v[12];
        float qA9 = qA5 + w[3] + w[4] + w[10] + w[11];
        float qB9 = qB5 + w[4] + w[5] + w[11] + w[12];
        float sA15 = sA9 + v[0] + v[1] + v[2] + v[12] + v[13] + v[14];
        float sB15 = sB9 + v[1] + v[2] + v[3] + v[13] + v[14] + v[15];
        float qA15 = qA9 + w[0] + w[1] + w[2] + w[12] + w[13] + w[14];
        float qB15 = qB9 + w[1] + w[2] + w[3] + w[13] + w[14] + w[15];
        int base = r * 76 + 4 * xh;
        *(float4*)&hsq[0][base] = make_float4(sA5, qA5, sB5, qB5);
        *(float4*)&hsq[1][base] = make_float4(sA9, qA9, sB9, qB9);
        *(float4*)&hsq[2][base] = make_float4(sA15, qA15, sB15, qB15);
    }
    __syncthreads();

    float wwin[3] = {fw[0] * 0.125f, fw[1] * 0.125f, fw[2] * 0.125f};
    float part[4] = {0.f, 0.f, 0.f, 0.f};
#pragma unroll
    for (int wi = 0; wi < 3; wi++) {
        const int wlen = (wi == 0) ? 5 : ((wi == 1) ? 9 : 15);
        const int r0 = 2 * yp + 7 - (wlen >> 1);
        const float inv = 1.0f / (float)(wlen * wlen);
        const float ww = wwin[wi];
        const float* basep = &hsq[wi][4 * xq];
        float4 first = *(const float4*)(basep + r0 * 76);
        float4 accv = first;
#pragma unroll
        for (int k = 1; k < wlen; k++) {
            float4 p = *(const float4*)(basep + (r0 + k) * 76);
            accv.x += p.x; accv.y += p.y; accv.z += p.z; accv.w += p.w;
        }
        float4 last = *(const float4*)(basep + (r0 + wlen) * 76);
        float sA1 = accv.x - first.x + last.x;
        float qA1 = accv.y - first.y + last.y;
        float sB1 = accv.z - first.z + last.z;
        float qB1 = accv.w - first.w + last.w;
        float mA0 = accv.x * inv, m2A0 = accv.y * inv;
        part[0] += ww * fast_sqrtf(fmaxf(m2A0 - mA0 * mA0, 0.f) + 1e-8f);
        float mB0 = accv.z * inv, m2B0 = accv.w * inv;
        part[1] += ww * fast_sqrtf(fmaxf(m2B0 - mB0 * mB0, 0.f) + 1e-8f);
        float mA1 = sA1 * inv, m2A1 = qA1 * inv;
        part[2] += ww * fast_sqrtf(fmaxf(m2A1 - mA1 * mA1, 0.f) + 1e-8f);
        float mB1 = sB1 * inv, m2B1 = qB1 * inv;
        part[3] += ww * fast_sqrtf(fmaxf(m2B1 - mB1 * mB1, 0.f) + 1e-8f);
    }

    float* dst = pbuf + (size_t)z * HW + (size_t)(by + 2 * yp) * W + bx + 2 * xq;
    *(float2*)dst = make_float2(part[0], part[1]);
    *(float2*)(dst + W) = make_float2(part[2], part[3]);
}

// ---------------- stdfuse B: sum 8 planes + fb, threshold + sigmoid ----------------
__global__ __launch_bounds__(256) void stdfuse_final(const float* __restrict__ pbuf,
                                                     const float* __restrict__ fb,
                                                     const float* __restrict__ stats,
                                                     int b, float* __restrict__ out) {
    int i4 = blockIdx.x * 256 + threadIdx.x;
    const float4* p4 = (const float4*)pbuf;
    float4 a = p4[i4];
#pragma unroll
    for (int z = 1; z < 8; z++) {
        float4 t = p4[(size_t)z * (HW / 4) + i4];
        a.x += t.x; a.y += t.y; a.z += t.z; a.w += t.w;
    }
    float fb0 = fb[0];
    float fused[4] = {a.x + fb0, a.y + fb0, a.z + fb0, a.w + fb0};
#pragma unroll
    for (int c = 0; c < 4; c++) {
        float lo = stats[(b * 4 + c) * 2];
        float up = stats[(b * 4 + c) * 2 + 1];
        float inv = 1.f / (up - lo);
        float4 o;
#pragma unroll
        for (int p = 0; p < 4; p++) {
            float ns = (fused[p] - lo) * inv;
            ns = fminf(fmaxf(ns, 0.f), 1.f);
            float v = 1.f / (1.f + fast_expf(3.f - 6.f * ns));
            if (p == 0) o.x = v; else if (p == 1) o.y = v; else if (p == 2) o.z = v; else o.w = v;
        }
        ((float4*)(out + ((size_t)(b * 4 + c)) * HW))[i4] = o;
    }
}

extern "C" void kernel_launch(void* const* d_in, const int* in_sizes, int n_in,
                              void* d_out, int out_size, void* d_ws, size_t ws_size,
                              hipStream_t stream) {
    (void)in_sizes; (void)n_in; (void)out_size; (void)ws_size;
    const float* x = (const float*)d_in[0];
    const float* w1 = (const float*)d_in[1];
    const float* b1 = (const float*)d_in[2];
    const float* w2 = (const float*)d_in[3];
    const float* b2 = (const float*)d_in[4];
    const float* w3 = (const float*)d_in[5];
    const float* b3 = (const float*)d_in[6];
    const float* chw = (const float*)d_in[7];
    const float* fw = (const float*)d_in[8];
    const float* fb = (const float*)d_in[9];
    float* out = (float*)d_out;

    char* ws = (char*)d_ws;
    float* stats = (float*)ws;                         // 32 f
    double* part = (double*)(ws + 256);                // 1024 d, ends 8448
    _Float16* w1a = (_Float16*)(ws + 8448);            // 4096 f16, ends 16640
    _Float16* w3f = (_Float16*)(ws + 24832);           // 6144 f16, ends 37120
    _Float16* w2bh = (_Float16*)(ws + 37120);          // 4608 f16, ends 46336
    _Float16* w2bl = (_Float16*)(ws + 46336);          // 4608 f16, ends 55552
    float* pbuf = (float*)(ws + 65536);                // 8*HW f32 = 32 MB
    float* f3 = (float*)(ws + 201392128);              // 32 MB

    stats_partial<<<512, 256, 0, stream>>>(x, part);
    stats_final_prep<<<1, 256, 0, stream>>>(part, chw, w1, w2, w3, stats, w1a, w3f, w2bh, w2bl);

    for (int b = 0; b < 4; b++) {
        const float* xb = x + (size_t)b * 4 * HW;
        conv123_mfma<<<dim3(35, 128), 256, 0, stream>>>(xb, w1a, b1, w2bh, w2bl, b2, w3f, b3, f3);
        stdfuse_partial<<<dim3(32, 32, 8), 256, 0, stream>>>(f3, fw, pbuf);
        stdfuse_final<<<1024, 256, 0, stream>>>(pbuf, fb, stats, b, out);
    }
}

// Round 2
// 638.254 us; speedup vs baseline: 1.2385x; 1.2385x over previous
//
#include <hip/hip_runtime.h>
#include <math.h>

#define H 1024
#define W 1024
#define HW (H * W)

typedef _Float16 half8 __attribute__((ext_vector_type(8)));
typedef _Float16 half4 __attribute__((ext_vector_type(4)));
typedef float f32x4 __attribute__((ext_vector_type(4)));

__device__ __forceinline__ float fast_sqrtf(float x) { return __builtin_amdgcn_sqrtf(x); }
__device__ __forceinline__ float fast_expf(float x) { return __builtin_amdgcn_exp2f(x * 1.44269504088896340736f); }

union U16 { unsigned short u; _Float16 f; };

__device__ __forceinline__ unsigned pack_hl(float v) {
    _Float16 h = (_Float16)v;
    _Float16 l = (_Float16)(v - (float)h);
    U16 a, b;
    a.f = h; b.f = l;
    return (unsigned)a.u | ((unsigned)b.u << 16);
}

// ---------------- stats pass 1: partial sum/sumsq per (b,c) chunk ----------------
__global__ __launch_bounds__(256) void stats_partial(const float* __restrict__ x,
                                                     double* __restrict__ part) {
    int blk = blockIdx.x;
    int bc = blk >> 5;
    int j = blk & 31;
    const float* p = x + (size_t)bc * HW + (size_t)j * (HW / 32);
    int tid = threadIdx.x;
    double s = 0.0, q = 0.0;
    const float4* p4 = (const float4*)p;
    for (int i = tid; i < (HW / 32) / 4; i += 256) {
        float4 v = p4[i];
        s += (double)v.x + (double)v.y + (double)v.z + (double)v.w;
        q += (double)v.x * v.x + (double)v.y * v.y + (double)v.z * v.z + (double)v.w * v.w;
    }
    __shared__ double ls[256], lq[256];
    ls[tid] = s;
    lq[tid] = q;
    __syncthreads();
    for (int ofs = 128; ofs > 0; ofs >>= 1) {
        if (tid < ofs) { ls[tid] += ls[tid + ofs]; lq[tid] += lq[tid + ofs]; }
        __syncthreads();
    }
    if (tid == 0) {
        part[blk * 2] = ls[0];
        part[blk * 2 + 1] = lq[0];
    }
}

// ---------------- stats pass 2 + weight prep ----------------
__global__ __launch_bounds__(256) void stats_final_prep(const double* __restrict__ part,
                                                        const float* __restrict__ chw,
                                                        const float* __restrict__ w1,
                                                        const float* __restrict__ w2,
                                                        const float* __restrict__ w3,
                                                        float* __restrict__ stats,
                                                        _Float16* __restrict__ w1a,
                                                        _Float16* __restrict__ w3f,
                                                        _Float16* __restrict__ w2bh,
                                                        _Float16* __restrict__ w2bl) {
    int tid = threadIdx.x;
    __shared__ float cw[4];
    if (tid == 0) {
        float m = fmaxf(fmaxf(chw[0], chw[1]), fmaxf(chw[2], chw[3]));
        float e0 = expf(chw[0] - m), e1 = expf(chw[1] - m);
        float e2 = expf(chw[2] - m), e3 = expf(chw[3] - m);
        float s = e0 + e1 + e2 + e3;
        cw[0] = e0 / s; cw[1] = e1 / s; cw[2] = e2 / s; cw[3] = e3 / s;
    }
    __syncthreads();
    if (tid < 16) {
        double s = 0.0, q = 0.0;
        for (int j = 0; j < 32; j++) {
            s += part[(tid * 32 + j) * 2];
            q += part[(tid * 32 + j) * 2 + 1];
        }
        double n = (double)HW;
        double var = (q - s * s / n) / (n - 1.0);
        if (var < 0) var = 0;
        float gs = (float)sqrt(var);
        int c = tid & 3;
        float gf = fminf(fmaxf(gs * 5.0f, 0.5f), 2.0f);
        float cf = fminf(fmaxf(gs * cw[c] * 2.0f, 0.8f), 1.2f);
        stats[tid * 2] = 0.05f * gf * cf;
        stats[tid * 2 + 1] = 0.20f * gf * cf;
    }
    for (int i = tid; i < 512; i += 256) {                 // conv1 A-frags
        int s = i >> 6, l = i & 63;
        int c = s >> 2, h = (s >> 1) & 1, hl = s & 1;
        int m = l & 15, cg = l >> 4;
        int co = h * 16 + m;
#pragma unroll
        for (int j = 0; j < 8; j++) {
            int k = c * 32 + cg * 8 + j;
            float v = 0.f;
            if (k < 36) {
                int t = k >> 2, ci = k & 3;
                v = w1[(co * 4 + ci) * 9 + t];
            }
            _Float16 hh = (_Float16)v;
            w1a[i * 8 + j] = hl ? (_Float16)(v - (float)hh) : hh;
        }
    }
    for (int idx = tid; idx < 576; idx += 256) {           // conv2 B-frags
        int t = idx >> 6, l = idx & 63;
        int co = l & 15, cg = l >> 4;
#pragma unroll
        for (int j = 0; j < 8; j++) {
            int ci = cg * 8 + j;
            float v = w2[(co * 32 + ci) * 9 + t];
            _Float16 hh = (_Float16)v;
            w2bh[idx * 8 + j] = hh;
            w2bl[idx * 8 + j] = (_Float16)(v - (float)hh);
        }
    }
    for (int idx = tid; idx < 768; idx += 256) {           // conv3 B-frags (12 sets x 64 lanes)
        int t = idx >> 6, l = idx & 63;
        int ky = t >> 2, grp = (t >> 1) & 1, hl = t & 1;
        int co = l & 15, bq = l >> 4;
#pragma unroll
        for (int j = 0; j < 8; j++) {
            int k = bq * 8 + j;
            float v = 0.f;
            if (co < 8) {
                if (grp == 0) {
                    int kxp = k >> 4, ci = k & 15;
                    v = w3[((co * 16 + ci) * 3 + ky) * 3 + kxp];
                } else if (k < 16) {
                    v = w3[((co * 16 + k) * 3 + ky) * 3 + 2];
                }
            }
            _Float16 hh = (_Float16)v;
            w3f[idx * 8 + j] = hl ? (_Float16)(v - (float)hh) : hh;
        }
    }
}

// ---------------- fused conv1+conv2, both via MFMA ----------------
__global__ __launch_bounds__(256) void conv12_mfma(const float* __restrict__ x,
                                                   const _Float16* __restrict__ w1a,
                                                   const float* __restrict__ b1,
                                                   const _Float16* __restrict__ wbh,
                                                   const _Float16* __restrict__ wbl,
                                                   const float* __restrict__ b2,
                                                   _Float16* __restrict__ f2n) {
    __shared__ __align__(16) char smem[50432];
    char* f1t = smem;                                  // 10*34*128 = 43520 B (swizzled)
    unsigned* xhl = (unsigned*)(smem + 43520);         // [4][12][36] u32 (f16h | f16l<<16)
    int tid = threadIdx.x;
    int lane = tid & 63;
    int wid = tid >> 6;
    int bx = blockIdx.x * 32, by = blockIdx.y * 8;
    int n = lane & 15, cg = lane >> 4;

    // phase 1: stage x halo (rows by-2..by+9, cols bx-2..bx+33) as packed f16 h/l
    for (int idx = tid; idx < 4 * 12 * 36; idx += 256) {
        int ci = idx / 432;
        int rem = idx - ci * 432;
        int r = rem / 36, c = rem - r * 36;
        int gy = by + r - 2, gx = bx + c - 2;
        float v = 0.f;
        if ((unsigned)gy < H && (unsigned)gx < W) v = x[ci * HW + gy * W + gx];
        xhl[idx] = pack_hl(v);
    }

    half8 Wf[8];
#pragma unroll
    for (int s = 0; s < 8; s++)
        Wf[s] = *(const half8*)(w1a + (s * 64 + lane) * 8);
    float bias1[8];
#pragma unroll
    for (int h = 0; h < 2; h++)
#pragma unroll
        for (int j = 0; j < 4; j++)
            bias1[h * 4 + j] = b1[h * 16 + cg * 4 + j];
    int t0 = 2 * cg, t1 = 2 * cg + 1;
    int dy0 = (t0 * 11) >> 5, dx0 = t0 - 3 * dy0;
    int dy1 = (t1 * 11) >> 5, dx1 = t1 - 3 * dy1;
    int off0 = dy0 * 36 + dx0, off1 = dy1 * 36 + dx1;
    __syncthreads();

    // phase 2: conv1 via MFMA; 22 tiles of 16 px cover the 340-px halo
#pragma unroll 1
    for (int tt = wid; tt < 22; tt += 4) {
        int p = tt * 16 + n;
        bool valid = p < 340;
        int pc = valid ? p : 339;
        int ry = pc / 34, cx = pc - ry * 34;
        int gy = by + ry - 1, gx = bx + cx - 1;
        bool ok = ((unsigned)gy < H) && ((unsigned)gx < W);
        int base = ry * 36 + cx;
        unsigned u0[8];
#pragma unroll
        for (int j = 0; j < 8; j++)
            u0[j] = xhl[(j & 3) * 432 + base + ((j < 4) ? off0 : off1)];
        half8 Xh0, Xl0;
#pragma unroll
        for (int j = 0; j < 8; j++) {
            U16 a; a.u = (unsigned short)u0[j]; Xh0[j] = a.f;
            U16 b; b.u = (unsigned short)(u0[j] >> 16); Xl0[j] = b.f;
        }
        half8 Xh1 = {0, 0, 0, 0, 0, 0, 0, 0}, Xl1 = {0, 0, 0, 0, 0, 0, 0, 0};
        if (cg == 0) {
#pragma unroll
            for (int j = 0; j < 4; j++) {
                unsigned v = xhl[j * 432 + base + 74];   // tap 8 (dy=2,dx=2)
                U16 a; a.u = (unsigned short)v; Xh1[j] = a.f;
                U16 b; b.u = (unsigned short)(v >> 16); Xl1[j] = b.f;
            }
        }
        f32x4 d0, d1;
#pragma unroll
        for (int j = 0; j < 4; j++) { d0[j] = bias1[j]; d1[j] = bias1[4 + j]; }
        d0 = __builtin_amdgcn_mfma_f32_16x16x32_f16(Wf[0], Xh0, d0, 0, 0, 0);
        d0 = __builtin_amdgcn_mfma_f32_16x16x32_f16(Wf[0], Xl0, d0, 0, 0, 0);
        d0 = __builtin_amdgcn_mfma_f32_16x16x32_f16(Wf[1], Xh0, d0, 0, 0, 0);
        d0 = __builtin_amdgcn_mfma_f32_16x16x32_f16(Wf[4], Xh1, d0, 0, 0, 0);
        d0 = __builtin_amdgcn_mfma_f32_16x16x32_f16(Wf[4], Xl1, d0, 0, 0, 0);
        d0 = __builtin_amdgcn_mfma_f32_16x16x32_f16(Wf[5], Xh1, d0, 0, 0, 0);
        d1 = __builtin_amdgcn_mfma_f32_16x16x32_f16(Wf[2], Xh0, d1, 0, 0, 0);
        d1 = __builtin_amdgcn_mfma_f32_16x16x32_f16(Wf[2], Xl0, d1, 0, 0, 0);
        d1 = __builtin_amdgcn_mfma_f32_16x16x32_f16(Wf[3], Xh0, d1, 0, 0, 0);
        d1 = __builtin_amdgcn_mfma_f32_16x16x32_f16(Wf[6], Xh1, d1, 0, 0, 0);
        d1 = __builtin_amdgcn_mfma_f32_16x16x32_f16(Wf[6], Xl1, d1, 0, 0, 0);
        d1 = __builtin_amdgcn_mfma_f32_16x16x32_f16(Wf[7], Xh1, d1, 0, 0, 0);
        if (valid) {
            int sw = (cx & 7) << 4;
            char* pxb = f1t + ry * 4352 + cx * 128;
#pragma unroll
            for (int h = 0; h < 2; h++) {
                f32x4 d = h ? d1 : d0;
                half4 hq, lq;
#pragma unroll
                for (int j = 0; j < 4; j++) {
                    float v = d[j];
                    v = v >= 0.f ? v : 0.2f * v;
                    v = ok ? v : 0.f;
                    _Float16 hv = (_Float16)v;
                    hq[j] = hv;
                    lq[j] = (_Float16)(v - (float)hv);
                }
                int q8 = (h * 4 + cg) * 8;
                *(half4*)(pxb + (q8 ^ sw)) = hq;
                *(half4*)(pxb + ((64 + q8) ^ sw)) = lq;
            }
        }
    }
    __syncthreads();

    // phase 3: conv2 via rolling-row f16x2 MFMA, A-frags from swizzled LDS
    int m = lane & 15, b = lane >> 4;
    int wx = wid & 1, wy = wid >> 1;
    half8 Bh[9], Bl[9];
#pragma unroll
    for (int t = 0; t < 9; t++) {
        Bh[t] = *(const half8*)(wbh + (t * 64 + lane) * 8);
        Bl[t] = *(const half8*)(wbl + (t * 64 + lane) * 8);
    }
    float bc = b2[m];
    f32x4 acc2[4];
#pragma unroll
    for (int r = 0; r < 4; r++) acc2[r] = (f32x4){bc, bc, bc, bc};
#pragma unroll
    for (int iy = 0; iy < 6; iy++) {
        int f1row = wy * 4 + iy;
        half8 ah[3], al[3];
#pragma unroll
        for (int kx = 0; kx < 3; kx++) {
            int pxi = wx * 16 + m + kx;
            int base = f1row * 4352 + pxi * 128;
            int sw = (pxi & 7) << 4;
            ah[kx] = *(const half8*)(f1t + base + ((b * 16) ^ sw));
            al[kx] = *(const half8*)(f1t + base + ((64 + b * 16) ^ sw));
        }
#pragma unroll
        for (int kx = 0; kx < 3; kx++) {
#pragma unroll
            for (int ry = 0; ry < 4; ry++) {
                if (ry >= iy - 2 && ry <= iy) {
                    const int t = (iy - ry) * 3 + kx;
                    acc2[ry] = __builtin_amdgcn_mfma_f32_16x16x32_f16(ah[kx], Bh[t], acc2[ry], 0, 0, 0);
                    acc2[ry] = __builtin_amdgcn_mfma_f32_16x16x32_f16(ah[kx], Bl[t], acc2[ry], 0, 0, 0);
                    acc2[ry] = __builtin_amdgcn_mfma_f32_16x16x32_f16(al[kx], Bh[t], acc2[ry], 0, 0, 0);
                }
            }
        }
    }
    __syncthreads();

    // epilogue: leaky -> LDS transpose -> split f16 h/l -> store f2n
    float* tbuf = (float*)smem;
    int x0 = bx + wx * 16;
    int y0 = by + wy * 4;
#pragma unroll
    for (int ry = 0; ry < 4; ry++) {
#pragma unroll
        for (int j = 0; j < 4; j++) {
            float v = acc2[ry][j];
            v = v >= 0.f ? v : 0.2f * v;
            tbuf[((wid * 4 + ry) * 16 + b * 4 + j) * 20 + m] = v;
        }
    }
    __syncthreads();
    int px = lane & 15;
    int halfco = (lane >> 4) & 1;
    int hl = lane >> 5;
#pragma unroll
    for (int ry = 0; ry < 4; ry++) {
        const float4* src = (const float4*)&tbuf[((wid * 4 + ry) * 16 + px) * 20 + halfco * 8];
        float4 a = src[0], b4 = src[1];
        float vv[8] = {a.x, a.y, a.z, a.w, b4.x, b4.y, b4.z, b4.w};
        half8 o;
#pragma unroll
        for (int j = 0; j < 8; j++) {
            float v = vv[j];
            _Float16 hh = (_Float16)v;
            o[j] = hl ? (_Float16)(v - (float)hh) : hh;
        }
        *(half8*)(f2n + ((size_t)(y0 + ry) * W + x0 + px) * 32 + hl * 16 + halfco * 8) = o;
    }
}

// ---------------- conv3 v2: LDS-staged f16x2 MFMA, 32x8 tile, branch-free ----------------
__global__ __launch_bounds__(256) void conv3_mfma(const _Float16* __restrict__ f2n,
                                                  const _Float16* __restrict__ w3f,
                                                  const float* __restrict__ bias,
                                                  float* __restrict__ f3) {
    __shared__ __align__(16) char st[10 * 34 * 80];    // 27200 B
    int tid = threadIdx.x;
    int lane = tid & 63;
    int wid = tid >> 6;
    int bx = blockIdx.x * 32, by = blockIdx.y * 8;

    // stage: rows by-1..by+8, px bx-1..bx+32, 4 x 16B chunks per px
    for (int idx = tid; idx < 1360; idx += 256) {
        int c = idx & 3;
        int rem = idx >> 2;
        int r = rem / 34, p = rem - r * 34;
        int gy = by + r - 1, gx = bx + p - 1;
        half8 v = {0, 0, 0, 0, 0, 0, 0, 0};
        if ((unsigned)gy < H && (unsigned)gx < W)
            v = *(const half8*)(f2n + ((size_t)gy * W + gx) * 32 + c * 8);
        *(half8*)(st + r * 2720 + p * 80 + c * 16) = v;
    }

    half8 F[12];
#pragma unroll
    for (int t = 0; t < 12; t++)
        F[t] = *(const half8*)(w3f + (t * 64 + lane) * 8);
    int m = lane & 15, b = lane >> 4;
    int halfco = b & 1, kxp = b >> 1;
    int wx = wid & 1, wy = wid >> 1;
    float bc = (m < 8) ? bias[m] : 0.f;
    f32x4 acc[4];
#pragma unroll
    for (int r = 0; r < 4; r++) acc[r] = (f32x4){bc, bc, bc, bc};
    int pA = wx * 16 + m + kxp;                        // halo-local px for A (kx -1,0)
    int pB = wx * 16 + m + 2;                          // halo-local px for B (kx +1)
    __syncthreads();

#pragma unroll
    for (int iy = 0; iy < 6; iy++) {
        const char* rp = st + (wy * 4 + iy) * 2720;
        half8 ka_h = *(const half8*)(rp + pA * 80 + halfco * 16);
        half8 ka_l = *(const half8*)(rp + pA * 80 + halfco * 16 + 32);
        half8 kb_h = *(const half8*)(rp + pB * 80 + halfco * 16);
        half8 kb_l = *(const half8*)(rp + pB * 80 + halfco * 16 + 32);
#pragma unroll
        for (int ry = 0; ry < 4; ry++) {
            if (ry >= iy - 2 && ry <= iy) {
                const int ky = iy - ry;
                acc[ry] = __builtin_amdgcn_mfma_f32_16x16x32_f16(ka_h, F[ky * 4 + 0], acc[ry], 0, 0, 0);
                acc[ry] = __builtin_amdgcn_mfma_f32_16x16x32_f16(ka_h, F[ky * 4 + 1], acc[ry], 0, 0, 0);
                acc[ry] = __builtin_amdgcn_mfma_f32_16x16x32_f16(ka_l, F[ky * 4 + 0], acc[ry], 0, 0, 0);
                acc[ry] = __builtin_amdgcn_mfma_f32_16x16x32_f16(kb_h, F[ky * 4 + 2], acc[ry], 0, 0, 0);
                acc[ry] = __builtin_amdgcn_mfma_f32_16x16x32_f16(kb_h, F[ky * 4 + 3], acc[ry], 0, 0, 0);
                acc[ry] = __builtin_amdgcn_mfma_f32_16x16x32_f16(kb_l, F[ky * 4 + 2], acc[ry], 0, 0, 0);
            }
        }
    }

    if (m < 8) {
#pragma unroll
        for (int ry = 0; ry < 4; ry++) {
            int y = by + wy * 4 + ry;
            *(float4*)(f3 + (size_t)m * HW + (size_t)y * W + bx + wx * 16 + b * 4) =
                make_float4(acc[ry][0], acc[ry][1], acc[ry][2], acc[ry][3]);
        }
    }
}

// ---------------- stdfuse (fused): 8-channel std maps + fusion + threshold + sigmoid ----------------
// One block = one 32x32 tile of ONE batch; loops the 8 f3 channels serially, accumulating
// the fusion-weighted std sum in registers. No pbuf round trip, no second kernel.
__global__ __launch_bounds__(256) void stdfuse_fused(const float* __restrict__ f3all,
                                                     const float* __restrict__ fw,
                                                     const float* __restrict__ fb,
                                                     const float* __restrict__ stats,
                                                     float* __restrict__ out) {
    __shared__ __align__(16) float raw[46 * 50];
    __shared__ __align__(16) float hsq[3][46 * 76];
    int tid = threadIdx.x;
    int xq = tid & 15, yp = tid >> 4;
    int bx = blockIdx.x * 32, by = blockIdx.y * 32;
    int batch = blockIdx.z;
    const float* f3 = f3all + (size_t)batch * 8 * HW;

    float wwin[3] = {fw[0] * 0.125f, fw[1] * 0.125f, fw[2] * 0.125f};
    float part[4] = {0.f, 0.f, 0.f, 0.f};

    for (int z = 0; z < 8; z++) {
        const float* src = f3 + (size_t)z * HW;
        // stage raw tile (46x46 halo, reflect) -- safe vs. prior iter: raw reads all
        // completed before the previous B-barrier.
        for (int idx = tid; idx < 2116; idx += 256) {
            int r = idx / 46, col = idx - r * 46;
            int gy = by + r - 7, gx = bx + col - 7;
            gy = gy < 0 ? -gy : (gy > 1023 ? 2046 - gy : gy);
            gx = gx < 0 ? -gx : (gx > 1023 ? 2046 - gx : gx);
            raw[r * 50 + col] = src[gy * W + gx];
        }
        __syncthreads();   // A: raw ready; prior part-phase hsq reads done (program order)

        for (int idx = tid; idx < 736; idx += 256) {
            int r = idx >> 4, xh = idx & 15;
            const float* rp = raw + r * 50 + 2 * xh;
            float v[16], w[16];
#pragma unroll
            for (int k = 0; k < 8; k++) {
                float2 p = *(const float2*)(rp + 2 * k);
                v[2 * k] = p.x; v[2 * k + 1] = p.y;
            }
#pragma unroll
            for (int k = 0; k < 16; k++) w[k] = v[k] * v[k];
            float ms = v[6] + v[7] + v[8] + v[9];
            float mq = w[6] + w[7] + w[8] + w[9];
            float sA5 = v[5] + ms, sB5 = ms + v[10];
            float qA5 = w[5] + mq, qB5 = mq + w[10];
            float sA9 = sA5 + v[3] + v[4] + v[10] + v[11];
            float sB9 = sB5 + v[4] + v[5] + v[11] + v[12];
            float qA9 = qA5 + w[3] + w[4] + w[10] + w[11];
            float qB9 = qB5 + w[4] + w[5] + w[11] + w[12];
            float sA15 = sA9 + v[0] + v[1] + v[2] + v[12] + v[13] + v[14];
            float sB15 = sB9 + v[1] + v[2] + v[3] + v[13] + v[14] + v[15];
            float qA15 = qA9 + w[0] + w[1] + w[2] + w[12] + w[13] + w[14];
            float qB15 = qB9 + w[1] + w[2] + w[3] + w[13] + w[14] + w[15];
            int base = r * 76 + 4 * xh;
            *(float4*)&hsq[0][base] = make_float4(sA5, qA5, sB5, qB5);
            *(float4*)&hsq[1][base] = make_float4(sA9, qA9, sB9, qB9);
            *(float4*)&hsq[2][base] = make_float4(sA15, qA15, sB15, qB15);
        }
        __syncthreads();   // B: hsq ready; all raw reads complete before next stage

#pragma unroll
        for (int wi = 0; wi < 3; wi++) {
            const int wlen = (wi == 0) ? 5 : ((wi == 1) ? 9 : 15);
            const int r0 = 2 * yp + 7 - (wlen >> 1);
            const float inv = 1.0f / (float)(wlen * wlen);
            const float ww = wwin[wi];
            const float* basep = &hsq[wi][4 * xq];
            float4 first = *(const float4*)(basep + r0 * 76);
            float4 accv = first;
#pragma unroll
            for (int k = 1; k < wlen; k++) {
                float4 p = *(const float4*)(basep + (r0 + k) * 76);
                accv.x += p.x; accv.y += p.y; accv.z += p.z; accv.w += p.w;
            }
            float4 last = *(const float4*)(basep + (r0 + wlen) * 76);
            float sA1 = accv.x - first.x + last.x;
            float qA1 = accv.y - first.y + last.y;
            float sB1 = accv.z - first.z + last.z;
            float qB1 = accv.w - first.w + last.w;
            float mA0 = accv.x * inv, m2A0 = accv.y * inv;
            part[0] += ww * fast_sqrtf(fmaxf(m2A0 - mA0 * mA0, 0.f) + 1e-8f);
            float mB0 = accv.z * inv, m2B0 = accv.w * inv;
            part[1] += ww * fast_sqrtf(fmaxf(m2B0 - mB0 * mB0, 0.f) + 1e-8f);
            float mA1 = sA1 * inv, m2A1 = qA1 * inv;
            part[2] += ww * fast_sqrtf(fmaxf(m2A1 - mA1 * mA1, 0.f) + 1e-8f);
            float mB1 = sB1 * inv, m2B1 = qB1 * inv;
            part[3] += ww * fast_sqrtf(fmaxf(m2B1 - mB1 * mB1, 0.f) + 1e-8f);
        }
        // no barrier needed here: next stage writes raw (disjoint from hsq);
        // hsq is rewritten only after barrier A of the next iteration.
    }

    // epilogue: fused value -> per-channel threshold + sigmoid, direct output write
    float fb0 = fb[0];
    int gy = by + 2 * yp, gx = bx + 2 * xq;
#pragma unroll
    for (int c = 0; c < 4; c++) {
        float lo = stats[(batch * 4 + c) * 2];
        float up = stats[(batch * 4 + c) * 2 + 1];
        float inv = 1.f / (up - lo);
        float v[4];
#pragma unroll
        for (int p = 0; p < 4; p++) {
            float ns = (part[p] + fb0 - lo) * inv;
            ns = fminf(fmaxf(ns, 0.f), 1.f);
            v[p] = 1.f / (1.f + fast_expf(3.f - 6.f * ns));
        }
        float* plane = out + ((size_t)(batch * 4 + c)) * HW;
        *(float2*)(plane + (size_t)gy * W + gx) = make_float2(v[0], v[1]);
        *(float2*)(plane + (size_t)(gy + 1) * W + gx) = make_float2(v[2], v[3]);
    }
}

extern "C" void kernel_launch(void* const* d_in, const int* in_sizes, int n_in,
                              void* d_out, int out_size, void* d_ws, size_t ws_size,
                              hipStream_t stream) {
    (void)in_sizes; (void)n_in; (void)out_size; (void)ws_size;
    const float* x = (const float*)d_in[0];
    const float* w1 = (const float*)d_in[1];
    const float* b1 = (const float*)d_in[2];
    const float* w2 = (const float*)d_in[3];
    const float* b2 = (const float*)d_in[4];
    const float* w3 = (const float*)d_in[5];
    const float* b3 = (const float*)d_in[6];
    const float* chw = (const float*)d_in[7];
    const float* fw = (const float*)d_in[8];
    const float* fb = (const float*)d_in[9];
    float* out = (float*)d_out;

    char* ws = (char*)d_ws;
    float* stats = (float*)ws;                         // 32 f
    double* part = (double*)(ws + 256);                // 1024 d, ends 8448
    _Float16* w1a = (_Float16*)(ws + 8448);            // 4096 f16, ends 16640
    _Float16* w3f = (_Float16*)(ws + 24832);           // 6144 f16, ends 37120
    _Float16* w2bh = (_Float16*)(ws + 37120);          // 4608 f16, ends 46336
    _Float16* w2bl = (_Float16*)(ws + 46336);          // 4608 f16, ends 55552
    float* f3all = (float*)(ws + 65536);               // 4 batches x 8 ch x HW f32 = 128 MB
    _Float16* f2n = (_Float16*)(ws + 134283264);       // 64 MB (reused per batch)

    stats_partial<<<512, 256, 0, stream>>>(x, part);
    stats_final_prep<<<1, 256, 0, stream>>>(part, chw, w1, w2, w3, stats, w1a, w3f, w2bh, w2bl);

    for (int b = 0; b < 4; b++) {
        const float* xb = x + (size_t)b * 4 * HW;
        conv12_mfma<<<dim3(32, 128), 256, 0, stream>>>(xb, w1a, b1, w2bh, w2bl, b2, f2n);
        conv3_mfma<<<dim3(32, 128), 256, 0, stream>>>(f2n, w3f, b3, f3all + (size_t)b * 8 * HW);
    }
    stdfuse_fused<<<dim3(32, 32, 4), 256, 0, stream>>>(f3all, fw, fb, stats, out);
}

// Round 3
// 531.047 us; speedup vs baseline: 1.4886x; 1.2019x over previous
//
#include <hip/hip_runtime.h>
#include <math.h>

#define H 1024
#define W 1024
#define HW (H * W)

typedef _Float16 half8 __attribute__((ext_vector_type(8)));
typedef _Float16 half4 __attribute__((ext_vector_type(4)));
typedef float f32x4 __attribute__((ext_vector_type(4)));

__device__ __forceinline__ float fast_sqrtf(float x) { return __builtin_amdgcn_sqrtf(x); }
__device__ __forceinline__ float fast_expf(float x) { return __builtin_amdgcn_exp2f(x * 1.44269504088896340736f); }

union U16 { unsigned short u; _Float16 f; };

__device__ __forceinline__ unsigned pack_hl(float v) {
    _Float16 h = (_Float16)v;
    _Float16 l = (_Float16)(v - (float)h);
    U16 a, b;
    a.f = h; b.f = l;
    return (unsigned)a.u | ((unsigned)b.u << 16);
}

// ---------------- stats pass 1: partial sum/sumsq per (b,c) chunk ----------------
__global__ __launch_bounds__(256) void stats_partial(const float* __restrict__ x,
                                                     double* __restrict__ part) {
    int blk = blockIdx.x;
    int bc = blk >> 5;
    int j = blk & 31;
    const float* p = x + (size_t)bc * HW + (size_t)j * (HW / 32);
    int tid = threadIdx.x;
    double s = 0.0, q = 0.0;
    const float4* p4 = (const float4*)p;
    for (int i = tid; i < (HW / 32) / 4; i += 256) {
        float4 v = p4[i];
        s += (double)v.x + (double)v.y + (double)v.z + (double)v.w;
        q += (double)v.x * v.x + (double)v.y * v.y + (double)v.z * v.z + (double)v.w * v.w;
    }
    __shared__ double ls[256], lq[256];
    ls[tid] = s;
    lq[tid] = q;
    __syncthreads();
    for (int ofs = 128; ofs > 0; ofs >>= 1) {
        if (tid < ofs) { ls[tid] += ls[tid + ofs]; lq[tid] += lq[tid + ofs]; }
        __syncthreads();
    }
    if (tid == 0) {
        part[blk * 2] = ls[0];
        part[blk * 2 + 1] = lq[0];
    }
}

// ---------------- stats pass 2 + weight prep ----------------
__global__ __launch_bounds__(256) void stats_final_prep(const double* __restrict__ part,
                                                        const float* __restrict__ chw,
                                                        const float* __restrict__ w1,
                                                        const float* __restrict__ w2,
                                                        const float* __restrict__ w3,
                                                        float* __restrict__ stats,
                                                        _Float16* __restrict__ w1a,
                                                        _Float16* __restrict__ w3f,
                                                        _Float16* __restrict__ w2bh,
                                                        _Float16* __restrict__ w2bl) {
    int tid = threadIdx.x;
    __shared__ float cw[4];
    if (tid == 0) {
        float m = fmaxf(fmaxf(chw[0], chw[1]), fmaxf(chw[2], chw[3]));
        float e0 = expf(chw[0] - m), e1 = expf(chw[1] - m);
        float e2 = expf(chw[2] - m), e3 = expf(chw[3] - m);
        float s = e0 + e1 + e2 + e3;
        cw[0] = e0 / s; cw[1] = e1 / s; cw[2] = e2 / s; cw[3] = e3 / s;
    }
    __syncthreads();
    if (tid < 16) {
        double s = 0.0, q = 0.0;
        for (int j = 0; j < 32; j++) {
            s += part[(tid * 32 + j) * 2];
            q += part[(tid * 32 + j) * 2 + 1];
        }
        double n = (double)HW;
        double var = (q - s * s / n) / (n - 1.0);
        if (var < 0) var = 0;
        float gs = (float)sqrt(var);
        int c = tid & 3;
        float gf = fminf(fmaxf(gs * 5.0f, 0.5f), 2.0f);
        float cf = fminf(fmaxf(gs * cw[c] * 2.0f, 0.8f), 1.2f);
        stats[tid * 2] = 0.05f * gf * cf;
        stats[tid * 2 + 1] = 0.20f * gf * cf;
    }
    for (int i = tid; i < 512; i += 256) {                 // conv1 A-frags
        int s = i >> 6, l = i & 63;
        int c = s >> 2, h = (s >> 1) & 1, hl = s & 1;
        int m = l & 15, cg = l >> 4;
        int co = h * 16 + m;
#pragma unroll
        for (int j = 0; j < 8; j++) {
            int k = c * 32 + cg * 8 + j;
            float v = 0.f;
            if (k < 36) {
                int t = k >> 2, ci = k & 3;
                v = w1[(co * 4 + ci) * 9 + t];
            }
            _Float16 hh = (_Float16)v;
            w1a[i * 8 + j] = hl ? (_Float16)(v - (float)hh) : hh;
        }
    }
    for (int idx = tid; idx < 576; idx += 256) {           // conv2 B-frags
        int t = idx >> 6, l = idx & 63;
        int co = l & 15, cg = l >> 4;
#pragma unroll
        for (int j = 0; j < 8; j++) {
            int ci = cg * 8 + j;
            float v = w2[(co * 32 + ci) * 9 + t];
            _Float16 hh = (_Float16)v;
            w2bh[idx * 8 + j] = hh;
            w2bl[idx * 8 + j] = (_Float16)(v - (float)hh);
        }
    }
    for (int idx = tid; idx < 768; idx += 256) {           // conv3 B-frags (12 sets x 64 lanes)
        int t = idx >> 6, l = idx & 63;
        int ky = t >> 2, grp = (t >> 1) & 1, hl = t & 1;
        int co = l & 15, bq = l >> 4;
#pragma unroll
        for (int j = 0; j < 8; j++) {
            int k = bq * 8 + j;
            float v = 0.f;
            if (co < 8) {
                if (grp == 0) {
                    int kxp = k >> 4, ci = k & 15;
                    v = w3[((co * 16 + ci) * 3 + ky) * 3 + kxp];
                } else if (k < 16) {
                    v = w3[((co * 16 + k) * 3 + ky) * 3 + 2];
                }
            }
            _Float16 hh = (_Float16)v;
            w3f[idx * 8 + j] = hl ? (_Float16)(v - (float)hh) : hh;
        }
    }
}

// ---------------- fused conv1+conv2, both via MFMA ----------------
__global__ __launch_bounds__(256) void conv12_mfma(const float* __restrict__ x,
                                                   const _Float16* __restrict__ w1a,
                                                   const float* __restrict__ b1,
                                                   const _Float16* __restrict__ wbh,
                                                   const _Float16* __restrict__ wbl,
                                                   const float* __restrict__ b2,
                                                   _Float16* __restrict__ f2n) {
    __shared__ __align__(16) char smem[50432];
    char* f1t = smem;                                  // 10*34*128 = 43520 B (swizzled)
    unsigned* xhl = (unsigned*)(smem + 43520);         // [4][12][36] u32 (f16h | f16l<<16)
    int tid = threadIdx.x;
    int lane = tid & 63;
    int wid = tid >> 6;
    int bx = blockIdx.x * 32, by = blockIdx.y * 8;
    int n = lane & 15, cg = lane >> 4;

    // phase 1: stage x halo (rows by-2..by+9, cols bx-2..bx+33) as packed f16 h/l
    for (int idx = tid; idx < 4 * 12 * 36; idx += 256) {
        int ci = idx / 432;
        int rem = idx - ci * 432;
        int r = rem / 36, c = rem - r * 36;
        int gy = by + r - 2, gx = bx + c - 2;
        float v = 0.f;
        if ((unsigned)gy < H && (unsigned)gx < W) v = x[ci * HW + gy * W + gx];
        xhl[idx] = pack_hl(v);
    }

    half8 Wf[8];
#pragma unroll
    for (int s = 0; s < 8; s++)
        Wf[s] = *(const half8*)(w1a + (s * 64 + lane) * 8);
    float bias1[8];
#pragma unroll
    for (int h = 0; h < 2; h++)
#pragma unroll
        for (int j = 0; j < 4; j++)
            bias1[h * 4 + j] = b1[h * 16 + cg * 4 + j];
    int t0 = 2 * cg, t1 = 2 * cg + 1;
    int dy0 = (t0 * 11) >> 5, dx0 = t0 - 3 * dy0;
    int dy1 = (t1 * 11) >> 5, dx1 = t1 - 3 * dy1;
    int off0 = dy0 * 36 + dx0, off1 = dy1 * 36 + dx1;
    __syncthreads();

    // phase 2: conv1 via MFMA; 22 tiles of 16 px cover the 340-px halo
#pragma unroll 1
    for (int tt = wid; tt < 22; tt += 4) {
        int p = tt * 16 + n;
        bool valid = p < 340;
        int pc = valid ? p : 339;
        int ry = pc / 34, cx = pc - ry * 34;
        int gy = by + ry - 1, gx = bx + cx - 1;
        bool ok = ((unsigned)gy < H) && ((unsigned)gx < W);
        int base = ry * 36 + cx;
        unsigned u0[8];
#pragma unroll
        for (int j = 0; j < 8; j++)
            u0[j] = xhl[(j & 3) * 432 + base + ((j < 4) ? off0 : off1)];
        half8 Xh0, Xl0;
#pragma unroll
        for (int j = 0; j < 8; j++) {
            U16 a; a.u = (unsigned short)u0[j]; Xh0[j] = a.f;
            U16 b; b.u = (unsigned short)(u0[j] >> 16); Xl0[j] = b.f;
        }
        half8 Xh1 = {0, 0, 0, 0, 0, 0, 0, 0}, Xl1 = {0, 0, 0, 0, 0, 0, 0, 0};
        if (cg == 0) {
#pragma unroll
            for (int j = 0; j < 4; j++) {
                unsigned v = xhl[j * 432 + base + 74];   // tap 8 (dy=2,dx=2)
                U16 a; a.u = (unsigned short)v; Xh1[j] = a.f;
                U16 b; b.u = (unsigned short)(v >> 16); Xl1[j] = b.f;
            }
        }
        f32x4 d0, d1;
#pragma unroll
        for (int j = 0; j < 4; j++) { d0[j] = bias1[j]; d1[j] = bias1[4 + j]; }
        d0 = __builtin_amdgcn_mfma_f32_16x16x32_f16(Wf[0], Xh0, d0, 0, 0, 0);
        d0 = __builtin_amdgcn_mfma_f32_16x16x32_f16(Wf[0], Xl0, d0, 0, 0, 0);
        d0 = __builtin_amdgcn_mfma_f32_16x16x32_f16(Wf[1], Xh0, d0, 0, 0, 0);
        d0 = __builtin_amdgcn_mfma_f32_16x16x32_f16(Wf[4], Xh1, d0, 0, 0, 0);
        d0 = __builtin_amdgcn_mfma_f32_16x16x32_f16(Wf[4], Xl1, d0, 0, 0, 0);
        d0 = __builtin_amdgcn_mfma_f32_16x16x32_f16(Wf[5], Xh1, d0, 0, 0, 0);
        d1 = __builtin_amdgcn_mfma_f32_16x16x32_f16(Wf[2], Xh0, d1, 0, 0, 0);
        d1 = __builtin_amdgcn_mfma_f32_16x16x32_f16(Wf[2], Xl0, d1, 0, 0, 0);
        d1 = __builtin_amdgcn_mfma_f32_16x16x32_f16(Wf[3], Xh0, d1, 0, 0, 0);
        d1 = __builtin_amdgcn_mfma_f32_16x16x32_f16(Wf[6], Xh1, d1, 0, 0, 0);
        d1 = __builtin_amdgcn_mfma_f32_16x16x32_f16(Wf[6], Xl1, d1, 0, 0, 0);
        d1 = __builtin_amdgcn_mfma_f32_16x16x32_f16(Wf[7], Xh1, d1, 0, 0, 0);
        if (valid) {
            int sw = (cx & 7) << 4;
            char* pxb = f1t + ry * 4352 + cx * 128;
#pragma unroll
            for (int h = 0; h < 2; h++) {
                f32x4 d = h ? d1 : d0;
                half4 hq, lq;
#pragma unroll
                for (int j = 0; j < 4; j++) {
                    float v = d[j];
                    v = v >= 0.f ? v : 0.2f * v;
                    v = ok ? v : 0.f;
                    _Float16 hv = (_Float16)v;
                    hq[j] = hv;
                    lq[j] = (_Float16)(v - (float)hv);
                }
                int q8 = (h * 4 + cg) * 8;
                *(half4*)(pxb + (q8 ^ sw)) = hq;
                *(half4*)(pxb + ((64 + q8) ^ sw)) = lq;
            }
        }
    }
    __syncthreads();

    // phase 3: conv2 via rolling-row f16x2 MFMA, A-frags from swizzled LDS
    int m = lane & 15, b = lane >> 4;
    int wx = wid & 1, wy = wid >> 1;
    half8 Bh[9], Bl[9];
#pragma unroll
    for (int t = 0; t < 9; t++) {
        Bh[t] = *(const half8*)(wbh + (t * 64 + lane) * 8);
        Bl[t] = *(const half8*)(wbl + (t * 64 + lane) * 8);
    }
    float bc = b2[m];
    f32x4 acc2[4];
#pragma unroll
    for (int r = 0; r < 4; r++) acc2[r] = (f32x4){bc, bc, bc, bc};
#pragma unroll
    for (int iy = 0; iy < 6; iy++) {
        int f1row = wy * 4 + iy;
        half8 ah[3], al[3];
#pragma unroll
        for (int kx = 0; kx < 3; kx++) {
            int pxi = wx * 16 + m + kx;
            int base = f1row * 4352 + pxi * 128;
            int sw = (pxi & 7) << 4;
            ah[kx] = *(const half8*)(f1t + base + ((b * 16) ^ sw));
            al[kx] = *(const half8*)(f1t + base + ((64 + b * 16) ^ sw));
        }
#pragma unroll
        for (int kx = 0; kx < 3; kx++) {
#pragma unroll
            for (int ry = 0; ry < 4; ry++) {
                if (ry >= iy - 2 && ry <= iy) {
                    const int t = (iy - ry) * 3 + kx;
                    acc2[ry] = __builtin_amdgcn_mfma_f32_16x16x32_f16(ah[kx], Bh[t], acc2[ry], 0, 0, 0);
                    acc2[ry] = __builtin_amdgcn_mfma_f32_16x16x32_f16(ah[kx], Bl[t], acc2[ry], 0, 0, 0);
                    acc2[ry] = __builtin_amdgcn_mfma_f32_16x16x32_f16(al[kx], Bh[t], acc2[ry], 0, 0, 0);
                }
            }
        }
    }
    __syncthreads();

    // epilogue: leaky -> LDS transpose -> split f16 h/l -> store f2n
    float* tbuf = (float*)smem;
    int x0 = bx + wx * 16;
    int y0 = by + wy * 4;
#pragma unroll
    for (int ry = 0; ry < 4; ry++) {
#pragma unroll
        for (int j = 0; j < 4; j++) {
            float v = acc2[ry][j];
            v = v >= 0.f ? v : 0.2f * v;
            tbuf[((wid * 4 + ry) * 16 + b * 4 + j) * 20 + m] = v;
        }
    }
    __syncthreads();
    int px = lane & 15;
    int halfco = (lane >> 4) & 1;
    int hl = lane >> 5;
#pragma unroll
    for (int ry = 0; ry < 4; ry++) {
        const float4* src = (const float4*)&tbuf[((wid * 4 + ry) * 16 + px) * 20 + halfco * 8];
        float4 a = src[0], b4 = src[1];
        float vv[8] = {a.x, a.y, a.z, a.w, b4.x, b4.y, b4.z, b4.w};
        half8 o;
#pragma unroll
        for (int j = 0; j < 8; j++) {
            float v = vv[j];
            _Float16 hh = (_Float16)v;
            o[j] = hl ? (_Float16)(v - (float)hh) : hh;
        }
        *(half8*)(f2n + ((size_t)(y0 + ry) * W + x0 + px) * 32 + hl * 16 + halfco * 8) = o;
    }
}

// ---------------- conv3 v2: LDS-staged f16x2 MFMA, 32x8 tile, branch-free ----------------
__global__ __launch_bounds__(256) void conv3_mfma(const _Float16* __restrict__ f2n,
                                                  const _Float16* __restrict__ w3f,
                                                  const float* __restrict__ bias,
                                                  float* __restrict__ f3) {
    __shared__ __align__(16) char st[10 * 34 * 80];    // 27200 B
    int tid = threadIdx.x;
    int lane = tid & 63;
    int wid = tid >> 6;
    int bx = blockIdx.x * 32, by = blockIdx.y * 8;

    // stage: rows by-1..by+8, px bx-1..bx+32, 4 x 16B chunks per px
    for (int idx = tid; idx < 1360; idx += 256) {
        int c = idx & 3;
        int rem = idx >> 2;
        int r = rem / 34, p = rem - r * 34;
        int gy = by + r - 1, gx = bx + p - 1;
        half8 v = {0, 0, 0, 0, 0, 0, 0, 0};
        if ((unsigned)gy < H && (unsigned)gx < W)
            v = *(const half8*)(f2n + ((size_t)gy * W + gx) * 32 + c * 8);
        *(half8*)(st + r * 2720 + p * 80 + c * 16) = v;
    }

    half8 F[12];
#pragma unroll
    for (int t = 0; t < 12; t++)
        F[t] = *(const half8*)(w3f + (t * 64 + lane) * 8);
    int m = lane & 15, b = lane >> 4;
    int halfco = b & 1, kxp = b >> 1;
    int wx = wid & 1, wy = wid >> 1;
    float bc = (m < 8) ? bias[m] : 0.f;
    f32x4 acc[4];
#pragma unroll
    for (int r = 0; r < 4; r++) acc[r] = (f32x4){bc, bc, bc, bc};
    int pA = wx * 16 + m + kxp;                        // halo-local px for A (kx -1,0)
    int pB = wx * 16 + m + 2;                          // halo-local px for B (kx +1)
    __syncthreads();

#pragma unroll
    for (int iy = 0; iy < 6; iy++) {
        const char* rp = st + (wy * 4 + iy) * 2720;
        half8 ka_h = *(const half8*)(rp + pA * 80 + halfco * 16);
        half8 ka_l = *(const half8*)(rp + pA * 80 + halfco * 16 + 32);
        half8 kb_h = *(const half8*)(rp + pB * 80 + halfco * 16);
        half8 kb_l = *(const half8*)(rp + pB * 80 + halfco * 16 + 32);
#pragma unroll
        for (int ry = 0; ry < 4; ry++) {
            if (ry >= iy - 2 && ry <= iy) {
                const int ky = iy - ry;
                acc[ry] = __builtin_amdgcn_mfma_f32_16x16x32_f16(ka_h, F[ky * 4 + 0], acc[ry], 0, 0, 0);
                acc[ry] = __builtin_amdgcn_mfma_f32_16x16x32_f16(ka_h, F[ky * 4 + 1], acc[ry], 0, 0, 0);
                acc[ry] = __builtin_amdgcn_mfma_f32_16x16x32_f16(ka_l, F[ky * 4 + 0], acc[ry], 0, 0, 0);
                acc[ry] = __builtin_amdgcn_mfma_f32_16x16x32_f16(kb_h, F[ky * 4 + 2], acc[ry], 0, 0, 0);
                acc[ry] = __builtin_amdgcn_mfma_f32_16x16x32_f16(kb_h, F[ky * 4 + 3], acc[ry], 0, 0, 0);
                acc[ry] = __builtin_amdgcn_mfma_f32_16x16x32_f16(kb_l, F[ky * 4 + 2], acc[ry], 0, 0, 0);
            }
        }
    }

    if (m < 8) {
#pragma unroll
        for (int ry = 0; ry < 4; ry++) {
            int y = by + wy * 4 + ry;
            *(float4*)(f3 + (size_t)m * HW + (size_t)y * W + bx + wx * 16 + b * 4) =
                make_float4(acc[ry][0], acc[ry][1], acc[ry][2], acc[ry][3]);
        }
    }
}

// ---------------- stdfuse (fused v2): 8-channel std maps + fusion + threshold + sigmoid ----------------
// v2: channel-invariant staging addresses hoisted to registers (reflect tables computed once),
// T14 async-STAGE split (issue z+1 loads under z's compute), dual-accumulator vertical sums.
__global__ __launch_bounds__(256) void stdfuse_fused(const float* __restrict__ f3all,
                                                     const float* __restrict__ fw,
                                                     const float* __restrict__ fb,
                                                     const float* __restrict__ stats,
                                                     float* __restrict__ out) {
    __shared__ __align__(16) float raw[46 * 50];
    __shared__ __align__(16) float hsq[3][46 * 76];
    __shared__ int rowOff[46];      // reflected gy * W (element offset)
    __shared__ int gxcol[46];       // reflected gx
    int tid = threadIdx.x;
    int xq = tid & 15, yp = tid >> 4;
    int bx = blockIdx.x * 32, by = blockIdx.y * 32;
    int batch = blockIdx.z;
    const float* f3 = f3all + (size_t)batch * 8 * HW;

    if (tid < 46) {
        int gy = by + tid - 7;
        gy = gy < 0 ? -gy : (gy > 1023 ? 2046 - gy : gy);
        rowOff[tid] = gy * W;
        int gx = bx + tid - 7;
        gx = gx < 0 ? -gx : (gx > 1023 ? 2046 - gx : gx);
        gxcol[tid] = gx;
    }
    __syncthreads();

    // per-thread staging task table (channel-invariant): 2116 = 8*256 + 68 tasks
    int goffB[9];   // global byte offset within a channel plane
    int laddB[9];   // LDS byte offset into raw
    const bool k8 = tid < 68;
#pragma unroll
    for (int k = 0; k < 9; k++) {
        int idx = tid + k * 256;
        int idc = idx < 2116 ? idx : 2115;
        int r = idc / 46, c = idc - r * 46;
        goffB[k] = (rowOff[r] + gxcol[c]) * 4;
        laddB[k] = (r * 50 + c) * 4;
    }

    float wwin[3] = {fw[0] * 0.125f, fw[1] * 0.125f, fw[2] * 0.125f};
    float part[4] = {0.f, 0.f, 0.f, 0.f};

    // prologue: load channel 0 into registers
    float stg[9];
    {
        const char* src = (const char*)f3;
#pragma unroll
        for (int k = 0; k < 8; k++) stg[k] = *(const float*)(src + goffB[k]);
        stg[8] = k8 ? *(const float*)(src + goffB[8]) : 0.f;
    }

    for (int z = 0; z < 8; z++) {
        // write staged registers to raw (safe: prior phase-2 raw reads ended at barrier B)
        char* rb = (char*)raw;
#pragma unroll
        for (int k = 0; k < 8; k++) *(float*)(rb + laddB[k]) = stg[k];
        if (k8) *(float*)(rb + laddB[8]) = stg[8];
        __syncthreads();   // A: raw ready; prior phase-3 hsq reads complete

        // T14: issue next channel's loads now; latency hides under phase 2+3
        if (z < 7) {
            const char* nsrc = (const char*)(f3 + (size_t)(z + 1) * HW);
#pragma unroll
            for (int k = 0; k < 8; k++) stg[k] = *(const float*)(nsrc + goffB[k]);
            if (k8) stg[8] = *(const float*)(nsrc + goffB[8]);
        }

        // phase 2: horizontal window sums (s, q) for A/B pixel pairs, all 46 rows
        for (int idx = tid; idx < 736; idx += 256) {
            int r = idx >> 4, xh = idx & 15;
            const float* rp = raw + r * 50 + 2 * xh;
            float v[16], w[16];
#pragma unroll
            for (int k = 0; k < 8; k++) {
                float2 p = *(const float2*)(rp + 2 * k);
                v[2 * k] = p.x; v[2 * k + 1] = p.y;
            }
#pragma unroll
            for (int k = 0; k < 16; k++) w[k] = v[k] * v[k];
            float ms = v[6] + v[7] + v[8] + v[9];
            float mq = w[6] + w[7] + w[8] + w[9];
            float sA5 = v[5] + ms, sB5 = ms + v[10];
            float qA5 = w[5] + mq, qB5 = mq + w[10];
            float sA9 = sA5 + v[3] + v[4] + v[10] + v[11];
            float sB9 = sB5 + v[4] + v[5] + v[11] + v[12];
            float qA9 = qA5 + w[3] + w[4] + w[10] + w[11];
            float qB9 = qB5 + w[4] + w[5] + w[11] + w[12];
            float sA15 = sA9 + v[0] + v[1] + v[2] + v[12] + v[13] + v[14];
            float sB15 = sB9 + v[1] + v[2] + v[3] + v[13] + v[14] + v[15];
            float qA15 = qA9 + w[0] + w[1] + w[2] + w[12] + w[13] + w[14];
            float qB15 = qB9 + w[1] + w[2] + w[3] + w[13] + w[14] + w[15];
            int base = r * 76 + 4 * xh;
            *(float4*)&hsq[0][base] = make_float4(sA5, qA5, sB5, qB5);
            *(float4*)&hsq[1][base] = make_float4(sA9, qA9, sB9, qB9);
            *(float4*)&hsq[2][base] = make_float4(sA15, qA15, sB15, qB15);
        }
        __syncthreads();   // B: hsq ready; all raw reads complete

        // phase 3: vertical sums (dual accumulators) + std finishing
#pragma unroll
        for (int wi = 0; wi < 3; wi++) {
            const int wlen = (wi == 0) ? 5 : ((wi == 1) ? 9 : 15);
            const int r0 = 2 * yp + 7 - (wlen >> 1);
            const float inv = 1.0f / (float)(wlen * wlen);
            const float ww = wwin[wi];
            const float* basep = &hsq[wi][4 * xq];
            float4 first = *(const float4*)(basep + r0 * 76);
            float4 e = first;
            float4 o = *(const float4*)(basep + (r0 + 1) * 76);
#pragma unroll
            for (int k = 2; k + 1 < wlen; k += 2) {
                float4 pe = *(const float4*)(basep + (r0 + k) * 76);
                float4 po = *(const float4*)(basep + (r0 + k + 1) * 76);
                e.x += pe.x; e.y += pe.y; e.z += pe.z; e.w += pe.w;
                o.x += po.x; o.y += po.y; o.z += po.z; o.w += po.w;
            }
            {   // last even row (wlen odd -> index wlen-1 is even)
                float4 pe = *(const float4*)(basep + (r0 + wlen - 1) * 76);
                e.x += pe.x; e.y += pe.y; e.z += pe.z; e.w += pe.w;
            }
            float4 accv = make_float4(e.x + o.x, e.y + o.y, e.z + o.z, e.w + o.w);
            float4 last = *(const float4*)(basep + (r0 + wlen) * 76);
            float sA1 = accv.x - first.x + last.x;
            float qA1 = accv.y - first.y + last.y;
            float sB1 = accv.z - first.z + last.z;
            float qB1 = accv.w - first.w + last.w;
            float mA0 = accv.x * inv, m2A0 = accv.y * inv;
            part[0] += ww * fast_sqrtf(fmaxf(m2A0 - mA0 * mA0, 0.f) + 1e-8f);
            float mB0 = accv.z * inv, m2B0 = accv.w * inv;
            part[1] += ww * fast_sqrtf(fmaxf(m2B0 - mB0 * mB0, 0.f) + 1e-8f);
            float mA1 = sA1 * inv, m2A1 = qA1 * inv;
            part[2] += ww * fast_sqrtf(fmaxf(m2A1 - mA1 * mA1, 0.f) + 1e-8f);
            float mB1 = sB1 * inv, m2B1 = qB1 * inv;
            part[3] += ww * fast_sqrtf(fmaxf(m2B1 - mB1 * mB1, 0.f) + 1e-8f);
        }
        // no barrier: next iter writes raw (disjoint from hsq); hsq rewritten only after next barrier A
    }

    // epilogue: fused value -> per-channel threshold + sigmoid, direct output write
    float fb0 = fb[0];
    int gy = by + 2 * yp, gx = bx + 2 * xq;
#pragma unroll
    for (int c = 0; c < 4; c++) {
        float lo = stats[(batch * 4 + c) * 2];
        float up = stats[(batch * 4 + c) * 2 + 1];
        float inv = 1.f / (up - lo);
        float v[4];
#pragma unroll
        for (int p = 0; p < 4; p++) {
            float ns = (part[p] + fb0 - lo) * inv;
            ns = fminf(fmaxf(ns, 0.f), 1.f);
            v[p] = 1.f / (1.f + fast_expf(3.f - 6.f * ns));
        }
        float* plane = out + ((size_t)(batch * 4 + c)) * HW;
        *(float2*)(plane + (size_t)gy * W + gx) = make_float2(v[0], v[1]);
        *(float2*)(plane + (size_t)(gy + 1) * W + gx) = make_float2(v[2], v[3]);
    }
}

extern "C" void kernel_launch(void* const* d_in, const int* in_sizes, int n_in,
                              void* d_out, int out_size, void* d_ws, size_t ws_size,
                              hipStream_t stream) {
    (void)in_sizes; (void)n_in; (void)out_size; (void)ws_size;
    const float* x = (const float*)d_in[0];
    const float* w1 = (const float*)d_in[1];
    const float* b1 = (const float*)d_in[2];
    const float* w2 = (const float*)d_in[3];
    const float* b2 = (const float*)d_in[4];
    const float* w3 = (const float*)d_in[5];
    const float* b3 = (const float*)d_in[6];
    const float* chw = (const float*)d_in[7];
    const float* fw = (const float*)d_in[8];
    const float* fb = (const float*)d_in[9];
    float* out = (float*)d_out;

    char* ws = (char*)d_ws;
    float* stats = (float*)ws;                         // 32 f
    double* part = (double*)(ws + 256);                // 1024 d, ends 8448
    _Float16* w1a = (_Float16*)(ws + 8448);            // 4096 f16, ends 16640
    _Float16* w3f = (_Float16*)(ws + 24832);           // 6144 f16, ends 37120
    _Float16* w2bh = (_Float16*)(ws + 37120);          // 4608 f16, ends 46336
    _Float16* w2bl = (_Float16*)(ws + 46336);          // 4608 f16, ends 55552
    float* f3all = (float*)(ws + 65536);               // 4 batches x 8 ch x HW f32 = 128 MB
    _Float16* f2n = (_Float16*)(ws + 134283264);       // 64 MB (reused per batch)

    stats_partial<<<512, 256, 0, stream>>>(x, part);
    stats_final_prep<<<1, 256, 0, stream>>>(part, chw, w1, w2, w3, stats, w1a, w3f, w2bh, w2bl);

    for (int b = 0; b < 4; b++) {
        const float* xb = x + (size_t)b * 4 * HW;
        conv12_mfma<<<dim3(32, 128), 256, 0, stream>>>(xb, w1a, b1, w2bh, w2bl, b2, f2n);
        conv3_mfma<<<dim3(32, 128), 256, 0, stream>>>(f2n, w3f, b3, f3all + (size_t)b * 8 * HW);
    }
    stdfuse_fused<<<dim3(32, 32, 4), 256, 0, stream>>>(f3all, fw, fb, stats, out);
}

// Round 4
// 524.274 us; speedup vs baseline: 1.5078x; 1.0129x over previous
//
#include <hip/hip_runtime.h>
#include <math.h>

#define H 1024
#define W 1024
#define HW (H * W)

typedef _Float16 half8 __attribute__((ext_vector_type(8)));
typedef _Float16 half4 __attribute__((ext_vector_type(4)));
typedef float f32x4 __attribute__((ext_vector_type(4)));

__device__ __forceinline__ float fast_sqrtf(float x) { return __builtin_amdgcn_sqrtf(x); }
__device__ __forceinline__ float fast_expf(float x) { return __builtin_amdgcn_exp2f(x * 1.44269504088896340736f); }

union U16 { unsigned short u; _Float16 f; };

__device__ __forceinline__ unsigned pack_hl(float v) {
    _Float16 h = (_Float16)v;
    _Float16 l = (_Float16)(v - (float)h);
    U16 a, b;
    a.f = h; b.f = l;
    return (unsigned)a.u | ((unsigned)b.u << 16);
}

// ---------------- stats pass 1: partial sum/sumsq per (b,c) chunk ----------------
__global__ __launch_bounds__(256) void stats_partial(const float* __restrict__ x,
                                                     double* __restrict__ part) {
    int blk = blockIdx.x;
    int bc = blk >> 5;
    int j = blk & 31;
    const float* p = x + (size_t)bc * HW + (size_t)j * (HW / 32);
    int tid = threadIdx.x;
    double s = 0.0, q = 0.0;
    const float4* p4 = (const float4*)p;
    for (int i = tid; i < (HW / 32) / 4; i += 256) {
        float4 v = p4[i];
        s += (double)v.x + (double)v.y + (double)v.z + (double)v.w;
        q += (double)v.x * v.x + (double)v.y * v.y + (double)v.z * v.z + (double)v.w * v.w;
    }
    __shared__ double ls[256], lq[256];
    ls[tid] = s;
    lq[tid] = q;
    __syncthreads();
    for (int ofs = 128; ofs > 0; ofs >>= 1) {
        if (tid < ofs) { ls[tid] += ls[tid + ofs]; lq[tid] += lq[tid + ofs]; }
        __syncthreads();
    }
    if (tid == 0) {
        part[blk * 2] = ls[0];
        part[blk * 2 + 1] = lq[0];
    }
}

// ---------------- stats pass 2 + weight prep ----------------
__global__ __launch_bounds__(256) void stats_final_prep(const double* __restrict__ part,
                                                        const float* __restrict__ chw,
                                                        const float* __restrict__ w1,
                                                        const float* __restrict__ w2,
                                                        const float* __restrict__ w3,
                                                        float* __restrict__ stats,
                                                        _Float16* __restrict__ w1a,
                                                        _Float16* __restrict__ w3f,
                                                        _Float16* __restrict__ w2bh,
                                                        _Float16* __restrict__ w2bl) {
    int tid = threadIdx.x;
    __shared__ float cw[4];
    if (tid == 0) {
        float m = fmaxf(fmaxf(chw[0], chw[1]), fmaxf(chw[2], chw[3]));
        float e0 = expf(chw[0] - m), e1 = expf(chw[1] - m);
        float e2 = expf(chw[2] - m), e3 = expf(chw[3] - m);
        float s = e0 + e1 + e2 + e3;
        cw[0] = e0 / s; cw[1] = e1 / s; cw[2] = e2 / s; cw[3] = e3 / s;
    }
    __syncthreads();
    if (tid < 16) {
        double s = 0.0, q = 0.0;
        for (int j = 0; j < 32; j++) {
            s += part[(tid * 32 + j) * 2];
            q += part[(tid * 32 + j) * 2 + 1];
        }
        double n = (double)HW;
        double var = (q - s * s / n) / (n - 1.0);
        if (var < 0) var = 0;
        float gs = (float)sqrt(var);
        int c = tid & 3;
        float gf = fminf(fmaxf(gs * 5.0f, 0.5f), 2.0f);
        float cf = fminf(fmaxf(gs * cw[c] * 2.0f, 0.8f), 1.2f);
        stats[tid * 2] = 0.05f * gf * cf;
        stats[tid * 2 + 1] = 0.20f * gf * cf;
    }
    for (int i = tid; i < 512; i += 256) {                 // conv1 A-frags
        int s = i >> 6, l = i & 63;
        int c = s >> 2, h = (s >> 1) & 1, hl = s & 1;
        int m = l & 15, cg = l >> 4;
        int co = h * 16 + m;
#pragma unroll
        for (int j = 0; j < 8; j++) {
            int k = c * 32 + cg * 8 + j;
            float v = 0.f;
            if (k < 36) {
                int t = k >> 2, ci = k & 3;
                v = w1[(co * 4 + ci) * 9 + t];
            }
            _Float16 hh = (_Float16)v;
            w1a[i * 8 + j] = hl ? (_Float16)(v - (float)hh) : hh;
        }
    }
    for (int idx = tid; idx < 576; idx += 256) {           // conv2 B-frags
        int t = idx >> 6, l = idx & 63;
        int co = l & 15, cg = l >> 4;
#pragma unroll
        for (int j = 0; j < 8; j++) {
            int ci = cg * 8 + j;
            float v = w2[(co * 32 + ci) * 9 + t];
            _Float16 hh = (_Float16)v;
            w2bh[idx * 8 + j] = hh;
            w2bl[idx * 8 + j] = (_Float16)(v - (float)hh);
        }
    }
    for (int idx = tid; idx < 768; idx += 256) {           // conv3 B-frags (12 sets x 64 lanes)
        int t = idx >> 6, l = idx & 63;
        int ky = t >> 2, grp = (t >> 1) & 1, hl = t & 1;
        int co = l & 15, bq = l >> 4;
#pragma unroll
        for (int j = 0; j < 8; j++) {
            int k = bq * 8 + j;
            float v = 0.f;
            if (co < 8) {
                if (grp == 0) {
                    int kxp = k >> 4, ci = k & 15;
                    v = w3[((co * 16 + ci) * 3 + ky) * 3 + kxp];
                } else if (k < 16) {
                    v = w3[((co * 16 + k) * 3 + ky) * 3 + 2];
                }
            }
            _Float16 hh = (_Float16)v;
            w3f[idx * 8 + j] = hl ? (_Float16)(v - (float)hh) : hh;
        }
    }
}

// ---------------- fused conv1+conv2, both via MFMA ----------------
// v4: conv2 MFMA operands swapped (D = W*X, lane holds 4 co of its own px) -> direct
// packed f2n store; tbuf transpose + 2 barriers removed. Multi-batch via blockIdx.z.
__global__ __launch_bounds__(256) void conv12_mfma(const float* __restrict__ x,
                                                   const _Float16* __restrict__ w1a,
                                                   const float* __restrict__ b1,
                                                   const _Float16* __restrict__ wbh,
                                                   const _Float16* __restrict__ wbl,
                                                   const float* __restrict__ b2,
                                                   _Float16* __restrict__ f2n,
                                                   size_t f2n_bstride, int batch0) {
    __shared__ __align__(16) char smem[50432];
    char* f1t = smem;                                  // 10*34*128 = 43520 B (swizzled)
    unsigned* xhl = (unsigned*)(smem + 43520);         // [4][12][36] u32 (f16h | f16l<<16)
    int tid = threadIdx.x;
    int lane = tid & 63;
    int wid = tid >> 6;
    int bx = blockIdx.x * 32, by = blockIdx.y * 8;
    int n = lane & 15, cg = lane >> 4;
    int batch = batch0 + blockIdx.z;
    const float* xb = x + (size_t)batch * 4 * HW;
    _Float16* f2nb = f2n + (size_t)blockIdx.z * f2n_bstride;

    // phase 1: stage x halo (rows by-2..by+9, cols bx-2..bx+33) as packed f16 h/l
    for (int idx = tid; idx < 4 * 12 * 36; idx += 256) {
        int ci = idx / 432;
        int rem = idx - ci * 432;
        int r = rem / 36, c = rem - r * 36;
        int gy = by + r - 2, gx = bx + c - 2;
        float v = 0.f;
        if ((unsigned)gy < H && (unsigned)gx < W) v = xb[ci * HW + gy * W + gx];
        xhl[idx] = pack_hl(v);
    }

    half8 Wf[8];
#pragma unroll
    for (int s = 0; s < 8; s++)
        Wf[s] = *(const half8*)(w1a + (s * 64 + lane) * 8);
    float bias1[8];
#pragma unroll
    for (int h = 0; h < 2; h++)
#pragma unroll
        for (int j = 0; j < 4; j++)
            bias1[h * 4 + j] = b1[h * 16 + cg * 4 + j];
    int t0 = 2 * cg, t1 = 2 * cg + 1;
    int dy0 = (t0 * 11) >> 5, dx0 = t0 - 3 * dy0;
    int dy1 = (t1 * 11) >> 5, dx1 = t1 - 3 * dy1;
    int off0 = dy0 * 36 + dx0, off1 = dy1 * 36 + dx1;
    __syncthreads();

    // phase 2: conv1 via MFMA; 22 tiles of 16 px cover the 340-px halo
#pragma unroll 1
    for (int tt = wid; tt < 22; tt += 4) {
        int p = tt * 16 + n;
        bool valid = p < 340;
        int pc = valid ? p : 339;
        int ry = pc / 34, cx = pc - ry * 34;
        int gy = by + ry - 1, gx = bx + cx - 1;
        bool ok = ((unsigned)gy < H) && ((unsigned)gx < W);
        int base = ry * 36 + cx;
        unsigned u0[8];
#pragma unroll
        for (int j = 0; j < 8; j++)
            u0[j] = xhl[(j & 3) * 432 + base + ((j < 4) ? off0 : off1)];
        half8 Xh0, Xl0;
#pragma unroll
        for (int j = 0; j < 8; j++) {
            U16 a; a.u = (unsigned short)u0[j]; Xh0[j] = a.f;
            U16 b; b.u = (unsigned short)(u0[j] >> 16); Xl0[j] = b.f;
        }
        half8 Xh1 = {0, 0, 0, 0, 0, 0, 0, 0}, Xl1 = {0, 0, 0, 0, 0, 0, 0, 0};
        if (cg == 0) {
#pragma unroll
            for (int j = 0; j < 4; j++) {
                unsigned v = xhl[j * 432 + base + 74];   // tap 8 (dy=2,dx=2)
                U16 a; a.u = (unsigned short)v; Xh1[j] = a.f;
                U16 b; b.u = (unsigned short)(v >> 16); Xl1[j] = b.f;
            }
        }
        f32x4 d0, d1;
#pragma unroll
        for (int j = 0; j < 4; j++) { d0[j] = bias1[j]; d1[j] = bias1[4 + j]; }
        d0 = __builtin_amdgcn_mfma_f32_16x16x32_f16(Wf[0], Xh0, d0, 0, 0, 0);
        d0 = __builtin_amdgcn_mfma_f32_16x16x32_f16(Wf[0], Xl0, d0, 0, 0, 0);
        d0 = __builtin_amdgcn_mfma_f32_16x16x32_f16(Wf[1], Xh0, d0, 0, 0, 0);
        d0 = __builtin_amdgcn_mfma_f32_16x16x32_f16(Wf[4], Xh1, d0, 0, 0, 0);
        d0 = __builtin_amdgcn_mfma_f32_16x16x32_f16(Wf[4], Xl1, d0, 0, 0, 0);
        d0 = __builtin_amdgcn_mfma_f32_16x16x32_f16(Wf[5], Xh1, d0, 0, 0, 0);
        d1 = __builtin_amdgcn_mfma_f32_16x16x32_f16(Wf[2], Xh0, d1, 0, 0, 0);
        d1 = __builtin_amdgcn_mfma_f32_16x16x32_f16(Wf[2], Xl0, d1, 0, 0, 0);
        d1 = __builtin_amdgcn_mfma_f32_16x16x32_f16(Wf[3], Xh0, d1, 0, 0, 0);
        d1 = __builtin_amdgcn_mfma_f32_16x16x32_f16(Wf[6], Xh1, d1, 0, 0, 0);
        d1 = __builtin_amdgcn_mfma_f32_16x16x32_f16(Wf[6], Xl1, d1, 0, 0, 0);
        d1 = __builtin_amdgcn_mfma_f32_16x16x32_f16(Wf[7], Xh1, d1, 0, 0, 0);
        if (valid) {
            int sw = (cx & 7) << 4;
            char* pxb = f1t + ry * 4352 + cx * 128;
#pragma unroll
            for (int h = 0; h < 2; h++) {
                f32x4 d = h ? d1 : d0;
                half4 hq, lq;
#pragma unroll
                for (int j = 0; j < 4; j++) {
                    float v = d[j];
                    v = v >= 0.f ? v : 0.2f * v;
                    v = ok ? v : 0.f;
                    _Float16 hv = (_Float16)v;
                    hq[j] = hv;
                    lq[j] = (_Float16)(v - (float)hv);
                }
                int q8 = (h * 4 + cg) * 8;
                *(half4*)(pxb + (q8 ^ sw)) = hq;
                *(half4*)(pxb + ((64 + q8) ^ sw)) = lq;
            }
        }
    }
    __syncthreads();

    // phase 3: conv2 via rolling-row f16x2 MFMA, operands swapped: D = W*X
    // lane: px = lane&15 (+wx*16), co = (lane>>4)*4 + j  -> direct store, no transpose
    int m = lane & 15, b = lane >> 4;
    int wx = wid & 1, wy = wid >> 1;
    half8 Bh[9], Bl[9];
#pragma unroll
    for (int t = 0; t < 9; t++) {
        Bh[t] = *(const half8*)(wbh + (t * 64 + lane) * 8);
        Bl[t] = *(const half8*)(wbl + (t * 64 + lane) * 8);
    }
    f32x4 binit;
#pragma unroll
    for (int j = 0; j < 4; j++) binit[j] = b2[b * 4 + j];
    f32x4 acc2[4];
#pragma unroll
    for (int r = 0; r < 4; r++) acc2[r] = binit;
#pragma unroll
    for (int iy = 0; iy < 6; iy++) {
        int f1row = wy * 4 + iy;
        half8 ah[3], al[3];
#pragma unroll
        for (int kx = 0; kx < 3; kx++) {
            int pxi = wx * 16 + m + kx;
            int base = f1row * 4352 + pxi * 128;
            int sw = (pxi & 7) << 4;
            ah[kx] = *(const half8*)(f1t + base + ((b * 16) ^ sw));
            al[kx] = *(const half8*)(f1t + base + ((64 + b * 16) ^ sw));
        }
#pragma unroll
        for (int kx = 0; kx < 3; kx++) {
#pragma unroll
            for (int ry = 0; ry < 4; ry++) {
                if (ry >= iy - 2 && ry <= iy) {
                    const int t = (iy - ry) * 3 + kx;
                    acc2[ry] = __builtin_amdgcn_mfma_f32_16x16x32_f16(Bh[t], ah[kx], acc2[ry], 0, 0, 0);
                    acc2[ry] = __builtin_amdgcn_mfma_f32_16x16x32_f16(Bl[t], ah[kx], acc2[ry], 0, 0, 0);
                    acc2[ry] = __builtin_amdgcn_mfma_f32_16x16x32_f16(Bh[t], al[kx], acc2[ry], 0, 0, 0);
                }
            }
        }
    }

    // epilogue: leaky -> pack f16 h/l -> direct store (lane owns px = bx+wx*16+m)
    int x0 = bx + wx * 16 + m;
    int y0 = by + wy * 4;
    int co_off = (b >> 1) * 8 + (b & 1) * 4;
#pragma unroll
    for (int ry = 0; ry < 4; ry++) {
        half4 hq, lq;
#pragma unroll
        for (int j = 0; j < 4; j++) {
            float v = acc2[ry][j];
            v = v >= 0.f ? v : 0.2f * v;
            _Float16 hv = (_Float16)v;
            hq[j] = hv;
            lq[j] = (_Float16)(v - (float)hv);
        }
        size_t base = ((size_t)(y0 + ry) * W + x0) * 32;
        *(half4*)(f2nb + base + co_off) = hq;
        *(half4*)(f2nb + base + 16 + co_off) = lq;
    }
}

// ---------------- conv3 v2: LDS-staged f16x2 MFMA, 32x8 tile, branch-free ----------------
__global__ __launch_bounds__(256) void conv3_mfma(const _Float16* __restrict__ f2n,
                                                  size_t f2n_bstride, int batch0,
                                                  const _Float16* __restrict__ w3f,
                                                  const float* __restrict__ bias,
                                                  float* __restrict__ f3all) {
    __shared__ __align__(16) char st[10 * 34 * 80];    // 27200 B
    int tid = threadIdx.x;
    int lane = tid & 63;
    int wid = tid >> 6;
    int bx = blockIdx.x * 32, by = blockIdx.y * 8;
    const _Float16* f2nb = f2n + (size_t)blockIdx.z * f2n_bstride;
    float* f3 = f3all + (size_t)(batch0 + blockIdx.z) * 8 * HW;

    // stage: rows by-1..by+8, px bx-1..bx+32, 4 x 16B chunks per px
    for (int idx = tid; idx < 1360; idx += 256) {
        int c = idx & 3;
        int rem = idx >> 2;
        int r = rem / 34, p = rem - r * 34;
        int gy = by + r - 1, gx = bx + p - 1;
        half8 v = {0, 0, 0, 0, 0, 0, 0, 0};
        if ((unsigned)gy < H && (unsigned)gx < W)
            v = *(const half8*)(f2nb + ((size_t)gy * W + gx) * 32 + c * 8);
        *(half8*)(st + r * 2720 + p * 80 + c * 16) = v;
    }

    half8 F[12];
#pragma unroll
    for (int t = 0; t < 12; t++)
        F[t] = *(const half8*)(w3f + (t * 64 + lane) * 8);
    int m = lane & 15, b = lane >> 4;
    int halfco = b & 1, kxp = b >> 1;
    int wx = wid & 1, wy = wid >> 1;
    float bc = (m < 8) ? bias[m] : 0.f;
    f32x4 acc[4];
#pragma unroll
    for (int r = 0; r < 4; r++) acc[r] = (f32x4){bc, bc, bc, bc};
    int pA = wx * 16 + m + kxp;                        // halo-local px for A (kx -1,0)
    int pB = wx * 16 + m + 2;                          // halo-local px for B (kx +1)
    __syncthreads();

#pragma unroll
    for (int iy = 0; iy < 6; iy++) {
        const char* rp = st + (wy * 4 + iy) * 2720;
        half8 ka_h = *(const half8*)(rp + pA * 80 + halfco * 16);
        half8 ka_l = *(const half8*)(rp + pA * 80 + halfco * 16 + 32);
        half8 kb_h = *(const half8*)(rp + pB * 80 + halfco * 16);
        half8 kb_l = *(const half8*)(rp + pB * 80 + halfco * 16 + 32);
#pragma unroll
        for (int ry = 0; ry < 4; ry++) {
            if (ry >= iy - 2 && ry <= iy) {
                const int ky = iy - ry;
                acc[ry] = __builtin_amdgcn_mfma_f32_16x16x32_f16(ka_h, F[ky * 4 + 0], acc[ry], 0, 0, 0);
                acc[ry] = __builtin_amdgcn_mfma_f32_16x16x32_f16(ka_h, F[ky * 4 + 1], acc[ry], 0, 0, 0);
                acc[ry] = __builtin_amdgcn_mfma_f32_16x16x32_f16(ka_l, F[ky * 4 + 0], acc[ry], 0, 0, 0);
                acc[ry] = __builtin_amdgcn_mfma_f32_16x16x32_f16(kb_h, F[ky * 4 + 2], acc[ry], 0, 0, 0);
                acc[ry] = __builtin_amdgcn_mfma_f32_16x16x32_f16(kb_h, F[ky * 4 + 3], acc[ry], 0, 0, 0);
                acc[ry] = __builtin_amdgcn_mfma_f32_16x16x32_f16(kb_l, F[ky * 4 + 2], acc[ry], 0, 0, 0);
            }
        }
    }

    if (m < 8) {
#pragma unroll
        for (int ry = 0; ry < 4; ry++) {
            int y = by + wy * 4 + ry;
            *(float4*)(f3 + (size_t)m * HW + (size_t)y * W + bx + wx * 16 + b * 4) =
                make_float4(acc[ry][0], acc[ry][1], acc[ry][2], acc[ry][3]);
        }
    }
}

// ---------------- stdfuse (fused v2): 8-channel std maps + fusion + threshold + sigmoid ----------------
__global__ __launch_bounds__(256) void stdfuse_fused(const float* __restrict__ f3all,
                                                     const float* __restrict__ fw,
                                                     const float* __restrict__ fb,
                                                     const float* __restrict__ stats,
                                                     float* __restrict__ out) {
    __shared__ __align__(16) float raw[46 * 50];
    __shared__ __align__(16) float hsq[3][46 * 76];
    __shared__ int rowOff[46];      // reflected gy * W (element offset)
    __shared__ int gxcol[46];       // reflected gx
    int tid = threadIdx.x;
    int xq = tid & 15, yp = tid >> 4;
    int bx = blockIdx.x * 32, by = blockIdx.y * 32;
    int batch = blockIdx.z;
    const float* f3 = f3all + (size_t)batch * 8 * HW;

    if (tid < 46) {
        int gy = by + tid - 7;
        gy = gy < 0 ? -gy : (gy > 1023 ? 2046 - gy : gy);
        rowOff[tid] = gy * W;
        int gx = bx + tid - 7;
        gx = gx < 0 ? -gx : (gx > 1023 ? 2046 - gx : gx);
        gxcol[tid] = gx;
    }
    __syncthreads();

    // per-thread staging task table (channel-invariant): 2116 = 8*256 + 68 tasks
    int goffB[9];   // global byte offset within a channel plane
    int laddB[9];   // LDS byte offset into raw
    const bool k8 = tid < 68;
#pragma unroll
    for (int k = 0; k < 9; k++) {
        int idx = tid + k * 256;
        int idc = idx < 2116 ? idx : 2115;
        int r = idc / 46, c = idc - r * 46;
        goffB[k] = (rowOff[r] + gxcol[c]) * 4;
        laddB[k] = (r * 50 + c) * 4;
    }

    float wwin[3] = {fw[0] * 0.125f, fw[1] * 0.125f, fw[2] * 0.125f};
    float part[4] = {0.f, 0.f, 0.f, 0.f};

    // prologue: load channel 0 into registers
    float stg[9];
    {
        const char* src = (const char*)f3;
#pragma unroll
        for (int k = 0; k < 8; k++) stg[k] = *(const float*)(src + goffB[k]);
        stg[8] = k8 ? *(const float*)(src + goffB[8]) : 0.f;
    }

    for (int z = 0; z < 8; z++) {
        // write staged registers to raw (safe: prior phase-2 raw reads ended at barrier B)
        char* rb = (char*)raw;
#pragma unroll
        for (int k = 0; k < 8; k++) *(float*)(rb + laddB[k]) = stg[k];
        if (k8) *(float*)(rb + laddB[8]) = stg[8];
        __syncthreads();   // A: raw ready; prior phase-3 hsq reads complete

        // T14: issue next channel's loads now; latency hides under phase 2+3
        if (z < 7) {
            const char* nsrc = (const char*)(f3 + (size_t)(z + 1) * HW);
#pragma unroll
            for (int k = 0; k < 8; k++) stg[k] = *(const float*)(nsrc + goffB[k]);
            if (k8) stg[8] = *(const float*)(nsrc + goffB[8]);
        }

        // phase 2: horizontal window sums (s, q) for A/B pixel pairs, all 46 rows
        for (int idx = tid; idx < 736; idx += 256) {
            int r = idx >> 4, xh = idx & 15;
            const float* rp = raw + r * 50 + 2 * xh;
            float v[16], w[16];
#pragma unroll
            for (int k = 0; k < 8; k++) {
                float2 p = *(const float2*)(rp + 2 * k);
                v[2 * k] = p.x; v[2 * k + 1] = p.y;
            }
#pragma unroll
            for (int k = 0; k < 16; k++) w[k] = v[k] * v[k];
            float ms = v[6] + v[7] + v[8] + v[9];
            float mq = w[6] + w[7] + w[8] + w[9];
            float sA5 = v[5] + ms, sB5 = ms + v[10];
            float qA5 = w[5] + mq, qB5 = mq + w[10];
            float sA9 = sA5 + v[3] + v[4] + v[10] + v[11];
            float sB9 = sB5 + v[4] + v[5] + v[11] + v[12];
            float qA9 = qA5 + w[3] + w[4] + w[10] + w[11];
            float qB9 = qB5 + w[4] + w[5] + w[11] + w[12];
            float sA15 = sA9 + v[0] + v[1] + v[2] + v[12] + v[13] + v[14];
            float sB15 = sB9 + v[1] + v[2] + v[3] + v[13] + v[14] + v[15];
            float qA15 = qA9 + w[0] + w[1] + w[2] + w[12] + w[13] + w[14];
            float qB15 = qB9 + w[1] + w[2] + w[3] + w[13] + w[14] + w[15];
            int base = r * 76 + 4 * xh;
            *(float4*)&hsq[0][base] = make_float4(sA5, qA5, sB5, qB5);
            *(float4*)&hsq[1][base] = make_float4(sA9, qA9, sB9, qB9);
            *(float4*)&hsq[2][base] = make_float4(sA15, qA15, sB15, qB15);
        }
        __syncthreads();   // B: hsq ready; all raw reads complete

        // phase 3: vertical sums (dual accumulators) + std finishing
#pragma unroll
        for (int wi = 0; wi < 3; wi++) {
            const int wlen = (wi == 0) ? 5 : ((wi == 1) ? 9 : 15);
            const int r0 = 2 * yp + 7 - (wlen >> 1);
            const float inv = 1.0f / (float)(wlen * wlen);
            const float ww = wwin[wi];
            const float* basep = &hsq[wi][4 * xq];
            float4 first = *(const float4*)(basep + r0 * 76);
            float4 e = first;
            float4 o = *(const float4*)(basep + (r0 + 1) * 76);
#pragma unroll
            for (int k = 2; k + 1 < wlen; k += 2) {
                float4 pe = *(const float4*)(basep + (r0 + k) * 76);
                float4 po = *(const float4*)(basep + (r0 + k + 1) * 76);
                e.x += pe.x; e.y += pe.y; e.z += pe.z; e.w += pe.w;
                o.x += po.x; o.y += po.y; o.z += po.z; o.w += po.w;
            }
            {   // last even row (wlen odd -> index wlen-1 is even)
                float4 pe = *(const float4*)(basep + (r0 + wlen - 1) * 76);
                e.x += pe.x; e.y += pe.y; e.z += pe.z; e.w += pe.w;
            }
            float4 accv = make_float4(e.x + o.x, e.y + o.y, e.z + o.z, e.w + o.w);
            float4 last = *(const float4*)(basep + (r0 + wlen) * 76);
            float sA1 = accv.x - first.x + last.x;
            float qA1 = accv.y - first.y + last.y;
            float sB1 = accv.z - first.z + last.z;
            float qB1 = accv.w - first.w + last.w;
            float mA0 = accv.x * inv, m2A0 = accv.y * inv;
            part[0] += ww * fast_sqrtf(fmaxf(m2A0 - mA0 * mA0, 0.f) + 1e-8f);
            float mB0 = accv.z * inv, m2B0 = accv.w * inv;
            part[1] += ww * fast_sqrtf(fmaxf(m2B0 - mB0 * mB0, 0.f) + 1e-8f);
            float mA1 = sA1 * inv, m2A1 = qA1 * inv;
            part[2] += ww * fast_sqrtf(fmaxf(m2A1 - mA1 * mA1, 0.f) + 1e-8f);
            float mB1 = sB1 * inv, m2B1 = qB1 * inv;
            part[3] += ww * fast_sqrtf(fmaxf(m2B1 - mB1 * mB1, 0.f) + 1e-8f);
        }
        // no barrier: next iter writes raw (disjoint from hsq); hsq rewritten only after next barrier A
    }

    // epilogue: fused value -> per-channel threshold + sigmoid, direct output write
    float fb0 = fb[0];
    int gy = by + 2 * yp, gx = bx + 2 * xq;
#pragma unroll
    for (int c = 0; c < 4; c++) {
        float lo = stats[(batch * 4 + c) * 2];
        float up = stats[(batch * 4 + c) * 2 + 1];
        float inv = 1.f / (up - lo);
        float v[4];
#pragma unroll
        for (int p = 0; p < 4; p++) {
            float ns = (part[p] + fb0 - lo) * inv;
            ns = fminf(fmaxf(ns, 0.f), 1.f);
            v[p] = 1.f / (1.f + fast_expf(3.f - 6.f * ns));
        }
        float* plane = out + ((size_t)(batch * 4 + c)) * HW;
        *(float2*)(plane + (size_t)gy * W + gx) = make_float2(v[0], v[1]);
        *(float2*)(plane + (size_t)(gy + 1) * W + gx) = make_float2(v[2], v[3]);
    }
}

extern "C" void kernel_launch(void* const* d_in, const int* in_sizes, int n_in,
                              void* d_out, int out_size, void* d_ws, size_t ws_size,
                              hipStream_t stream) {
    (void)in_sizes; (void)n_in; (void)out_size;
    const float* x = (const float*)d_in[0];
    const float* w1 = (const float*)d_in[1];
    const float* b1 = (const float*)d_in[2];
    const float* w2 = (const float*)d_in[3];
    const float* b2 = (const float*)d_in[4];
    const float* w3 = (const float*)d_in[5];
    const float* b3 = (const float*)d_in[6];
    const float* chw = (const float*)d_in[7];
    const float* fw = (const float*)d_in[8];
    const float* fb = (const float*)d_in[9];
    float* out = (float*)d_out;

    char* ws = (char*)d_ws;
    float* stats = (float*)ws;                         // 32 f
    double* part = (double*)(ws + 256);                // 1024 d, ends 8448
    _Float16* w1a = (_Float16*)(ws + 8448);            // 4096 f16, ends 16640
    _Float16* w3f = (_Float16*)(ws + 24832);           // 6144 f16, ends 37120
    _Float16* w2bh = (_Float16*)(ws + 37120);          // 4608 f16, ends 46336
    _Float16* w2bl = (_Float16*)(ws + 46336);          // 4608 f16, ends 55552
    float* f3all = (float*)(ws + 65536);               // 4 batches x 8 ch x HW f32 = 128 MB
    _Float16* f2n = (_Float16*)(ws + 134283264);       // 1 or 4 planes of 64 MB

    // wide mode: 4 f2n planes -> single conv12 + single conv3 dispatch (needs 384.06 MB ws)
    const size_t WIDE_WS = 134283264ULL + 4ULL * 32 * HW * sizeof(_Float16);
    bool wide = ws_size >= WIDE_WS;

    stats_partial<<<512, 256, 0, stream>>>(x, part);
    stats_final_prep<<<1, 256, 0, stream>>>(part, chw, w1, w2, w3, stats, w1a, w3f, w2bh, w2bl);

    if (wide) {
        size_t bstride = (size_t)32 * HW;
        conv12_mfma<<<dim3(32, 128, 4), 256, 0, stream>>>(x, w1a, b1, w2bh, w2bl, b2,
                                                          f2n, bstride, 0);
        conv3_mfma<<<dim3(32, 128, 4), 256, 0, stream>>>(f2n, bstride, 0, w3f, b3, f3all);
    } else {
        for (int b = 0; b < 4; b++) {
            conv12_mfma<<<dim3(32, 128, 1), 256, 0, stream>>>(x, w1a, b1, w2bh, w2bl, b2,
                                                              f2n, 0, b);
            conv3_mfma<<<dim3(32, 128, 1), 256, 0, stream>>>(f2n, 0, b, w3f, b3, f3all);
        }
    }
    stdfuse_fused<<<dim3(32, 32, 4), 256, 0, stream>>>(f3all, fw, fb, stats, out);
}

// Round 5
// 516.590 us; speedup vs baseline: 1.5302x; 1.0149x over previous
//
#include <hip/hip_runtime.h>
#include <math.h>

#define H 1024
#define W 1024
#define HW (H * W)

typedef _Float16 half8 __attribute__((ext_vector_type(8)));
typedef _Float16 half4 __attribute__((ext_vector_type(4)));
typedef float f32x4 __attribute__((ext_vector_type(4)));
typedef unsigned uint4v __attribute__((ext_vector_type(4)));

__device__ __forceinline__ float fast_sqrtf(float x) { return __builtin_amdgcn_sqrtf(x); }
__device__ __forceinline__ float fast_expf(float x) { return __builtin_amdgcn_exp2f(x * 1.44269504088896340736f); }

union U16 { unsigned short u; _Float16 f; };

__device__ __forceinline__ unsigned pack_hl(float v) {
    _Float16 h = (_Float16)v;
    _Float16 l = (_Float16)(v - (float)h);
    U16 a, b;
    a.f = h; b.f = l;
    return (unsigned)a.u | ((unsigned)b.u << 16);
}

// unpack 8 packed u32 (f16h | f16l<<16) into the h-plane / l-plane half8 via v_perm_b32
__device__ __forceinline__ half8 unpack_lo8(const unsigned* u) {
    uint4v a;
    a.x = __builtin_amdgcn_perm(u[1], u[0], 0x05040100);
    a.y = __builtin_amdgcn_perm(u[3], u[2], 0x05040100);
    a.z = __builtin_amdgcn_perm(u[5], u[4], 0x05040100);
    a.w = __builtin_amdgcn_perm(u[7], u[6], 0x05040100);
    return __builtin_bit_cast(half8, a);
}
__device__ __forceinline__ half8 unpack_hi8(const unsigned* u) {
    uint4v a;
    a.x = __builtin_amdgcn_perm(u[1], u[0], 0x07060302);
    a.y = __builtin_amdgcn_perm(u[3], u[2], 0x07060302);
    a.z = __builtin_amdgcn_perm(u[5], u[4], 0x07060302);
    a.w = __builtin_amdgcn_perm(u[7], u[6], 0x07060302);
    return __builtin_bit_cast(half8, a);
}
__device__ __forceinline__ half8 unpack_lo4(const unsigned* u) {
    uint4v a;
    a.x = __builtin_amdgcn_perm(u[1], u[0], 0x05040100);
    a.y = __builtin_amdgcn_perm(u[3], u[2], 0x05040100);
    a.z = 0; a.w = 0;
    return __builtin_bit_cast(half8, a);
}
__device__ __forceinline__ half8 unpack_hi4(const unsigned* u) {
    uint4v a;
    a.x = __builtin_amdgcn_perm(u[1], u[0], 0x07060302);
    a.y = __builtin_amdgcn_perm(u[3], u[2], 0x07060302);
    a.z = 0; a.w = 0;
    return __builtin_bit_cast(half8, a);
}

// ---------------- stats pass 1: partial sum/sumsq per (b,c) chunk ----------------
__global__ __launch_bounds__(256) void stats_partial(const float* __restrict__ x,
                                                     double* __restrict__ part) {
    int blk = blockIdx.x;
    int bc = blk >> 5;
    int j = blk & 31;
    const float* p = x + (size_t)bc * HW + (size_t)j * (HW / 32);
    int tid = threadIdx.x;
    double s = 0.0, q = 0.0;
    const float4* p4 = (const float4*)p;
    for (int i = tid; i < (HW / 32) / 4; i += 256) {
        float4 v = p4[i];
        s += (double)v.x + (double)v.y + (double)v.z + (double)v.w;
        q += (double)v.x * v.x + (double)v.y * v.y + (double)v.z * v.z + (double)v.w * v.w;
    }
    __shared__ double ls[256], lq[256];
    ls[tid] = s;
    lq[tid] = q;
    __syncthreads();
    for (int ofs = 128; ofs > 0; ofs >>= 1) {
        if (tid < ofs) { ls[tid] += ls[tid + ofs]; lq[tid] += lq[tid + ofs]; }
        __syncthreads();
    }
    if (tid == 0) {
        part[blk * 2] = ls[0];
        part[blk * 2 + 1] = lq[0];
    }
}

// ---------------- stats pass 2 + weight prep ----------------
__global__ __launch_bounds__(256) void stats_final_prep(const double* __restrict__ part,
                                                        const float* __restrict__ chw,
                                                        const float* __restrict__ w1,
                                                        const float* __restrict__ w2,
                                                        const float* __restrict__ w3,
                                                        float* __restrict__ stats,
                                                        _Float16* __restrict__ w1a,
                                                        _Float16* __restrict__ w3f,
                                                        _Float16* __restrict__ w2bh,
                                                        _Float16* __restrict__ w2bl) {
    int tid = threadIdx.x;
    __shared__ float cw[4];
    if (tid == 0) {
        float m = fmaxf(fmaxf(chw[0], chw[1]), fmaxf(chw[2], chw[3]));
        float e0 = expf(chw[0] - m), e1 = expf(chw[1] - m);
        float e2 = expf(chw[2] - m), e3 = expf(chw[3] - m);
        float s = e0 + e1 + e2 + e3;
        cw[0] = e0 / s; cw[1] = e1 / s; cw[2] = e2 / s; cw[3] = e3 / s;
    }
    __syncthreads();
    if (tid < 16) {
        double s = 0.0, q = 0.0;
        for (int j = 0; j < 32; j++) {
            s += part[(tid * 32 + j) * 2];
            q += part[(tid * 32 + j) * 2 + 1];
        }
        double n = (double)HW;
        double var = (q - s * s / n) / (n - 1.0);
        if (var < 0) var = 0;
        float gs = (float)sqrt(var);
        int c = tid & 3;
        float gf = fminf(fmaxf(gs * 5.0f, 0.5f), 2.0f);
        float cf = fminf(fmaxf(gs * cw[c] * 2.0f, 0.8f), 1.2f);
        stats[tid * 2] = 0.05f * gf * cf;
        stats[tid * 2 + 1] = 0.20f * gf * cf;
    }
    for (int i = tid; i < 512; i += 256) {                 // conv1 A-frags
        int s = i >> 6, l = i & 63;
        int c = s >> 2, h = (s >> 1) & 1, hl = s & 1;
        int m = l & 15, cg = l >> 4;
        int co = h * 16 + m;
#pragma unroll
        for (int j = 0; j < 8; j++) {
            int k = c * 32 + cg * 8 + j;
            float v = 0.f;
            if (k < 36) {
                int t = k >> 2, ci = k & 3;
                v = w1[(co * 4 + ci) * 9 + t];
            }
            _Float16 hh = (_Float16)v;
            w1a[i * 8 + j] = hl ? (_Float16)(v - (float)hh) : hh;
        }
    }
    for (int idx = tid; idx < 576; idx += 256) {           // conv2 B-frags
        int t = idx >> 6, l = idx & 63;
        int co = l & 15, cg = l >> 4;
#pragma unroll
        for (int j = 0; j < 8; j++) {
            int ci = cg * 8 + j;
            float v = w2[(co * 32 + ci) * 9 + t];
            _Float16 hh = (_Float16)v;
            w2bh[idx * 8 + j] = hh;
            w2bl[idx * 8 + j] = (_Float16)(v - (float)hh);
        }
    }
    for (int idx = tid; idx < 768; idx += 256) {           // conv3 B-frags (12 sets x 64 lanes)
        int t = idx >> 6, l = idx & 63;
        int ky = t >> 2, grp = (t >> 1) & 1, hl = t & 1;
        int co = l & 15, bq = l >> 4;
#pragma unroll
        for (int j = 0; j < 8; j++) {
            int k = bq * 8 + j;
            float v = 0.f;
            if (co < 8) {
                if (grp == 0) {
                    int kxp = k >> 4, ci = k & 15;
                    v = w3[((co * 16 + ci) * 3 + ky) * 3 + kxp];
                } else if (k < 16) {
                    v = w3[((co * 16 + k) * 3 + ky) * 3 + 2];
                }
            }
            _Float16 hh = (_Float16)v;
            w3f[idx * 8 + j] = hl ? (_Float16)(v - (float)hh) : hh;
        }
    }
}

// ---------------- fused conv1+conv2, both via MFMA ----------------
// v5: incremental staging addressing (no divides), perm-based f16 unpack, conv2
// weights hoisted above the first barrier (latency hidden under conv1).
__global__ __launch_bounds__(256, 3) void conv12_mfma(const float* __restrict__ x,
                                                      const _Float16* __restrict__ w1a,
                                                      const float* __restrict__ b1,
                                                      const _Float16* __restrict__ wbh,
                                                      const _Float16* __restrict__ wbl,
                                                      const float* __restrict__ b2,
                                                      _Float16* __restrict__ f2n) {
    __shared__ __align__(16) char smem[50432];
    char* f1t = smem;                                  // 10*34*128 = 43520 B (swizzled)
    unsigned* xhl = (unsigned*)(smem + 43520);         // [4][12][36] u32 (f16h | f16l<<16)
    int tid = threadIdx.x;
    int lane = tid & 63;
    int wid = tid >> 6;
    int bx = blockIdx.x * 32, by = blockIdx.y * 8;
    int n = lane & 15, cg = lane >> 4;
    int m = lane & 15, b = lane >> 4;

    // phase 1: stage x halo (rows by-2..by+9, cols bx-2..bx+33) as packed f16 h/l.
    // idx = ci*432 + r*36 + c walked incrementally (step 256 = +7 rows +4 cols).
    {
        int idx = tid;
        int r = tid / 36, c = tid - r * 36, ci = 0;
#pragma unroll
        for (int it = 0; it < 7; ++it) {
            if (idx < 1728) {
                int gy = by + r - 2, gx = bx + c - 2;
                float v = 0.f;
                if ((unsigned)gy < H && (unsigned)gx < W) v = x[ci * HW + gy * W + gx];
                xhl[idx] = pack_hl(v);
            }
            idx += 256;
            c += 4; if (c >= 36) { c -= 36; r += 1; }
            r += 7; if (r >= 12) { r -= 12; ci += 1; }
        }
    }

    half8 Wf[8];
#pragma unroll
    for (int s = 0; s < 8; s++)
        Wf[s] = *(const half8*)(w1a + (s * 64 + lane) * 8);
    float bias1[8];
#pragma unroll
    for (int h = 0; h < 2; h++)
#pragma unroll
        for (int j = 0; j < 4; j++)
            bias1[h * 4 + j] = b1[h * 16 + cg * 4 + j];
    // conv2 weights hoisted: independent global loads, latency hides under conv1
    half8 Bh[9], Bl[9];
#pragma unroll
    for (int t = 0; t < 9; t++) {
        Bh[t] = *(const half8*)(wbh + (t * 64 + lane) * 8);
        Bl[t] = *(const half8*)(wbl + (t * 64 + lane) * 8);
    }
    f32x4 binit;
#pragma unroll
    for (int j = 0; j < 4; j++) binit[j] = b2[b * 4 + j];

    int t0 = 2 * cg, t1 = 2 * cg + 1;
    int dy0 = (t0 * 11) >> 5, dx0 = t0 - 3 * dy0;
    int dy1 = (t1 * 11) >> 5, dx1 = t1 - 3 * dy1;
    int off0 = dy0 * 36 + dx0, off1 = dy1 * 36 + dx1;
    __syncthreads();

    // phase 2: conv1 via MFMA; 22 tiles of 16 px cover the 340-px halo
#pragma unroll 1
    for (int tt = wid; tt < 22; tt += 4) {
        int p = tt * 16 + n;
        bool valid = p < 340;
        int pc = valid ? p : 339;
        int ry = pc / 34, cx = pc - ry * 34;
        int gy = by + ry - 1, gx = bx + cx - 1;
        bool ok = ((unsigned)gy < H) && ((unsigned)gx < W);
        int base = ry * 36 + cx;
        unsigned u0[8];
#pragma unroll
        for (int j = 0; j < 8; j++)
            u0[j] = xhl[(j & 3) * 432 + base + ((j < 4) ? off0 : off1)];
        half8 Xh0 = unpack_lo8(u0);
        half8 Xl0 = unpack_hi8(u0);
        half8 Xh1 = {0, 0, 0, 0, 0, 0, 0, 0}, Xl1 = {0, 0, 0, 0, 0, 0, 0, 0};
        if (cg == 0) {
            unsigned u1[4];
#pragma unroll
            for (int j = 0; j < 4; j++)
                u1[j] = xhl[j * 432 + base + 74];       // tap 8 (dy=2,dx=2)
            Xh1 = unpack_lo4(u1);
            Xl1 = unpack_hi4(u1);
        }
        f32x4 d0, d1;
#pragma unroll
        for (int j = 0; j < 4; j++) { d0[j] = bias1[j]; d1[j] = bias1[4 + j]; }
        d0 = __builtin_amdgcn_mfma_f32_16x16x32_f16(Wf[0], Xh0, d0, 0, 0, 0);
        d0 = __builtin_amdgcn_mfma_f32_16x16x32_f16(Wf[0], Xl0, d0, 0, 0, 0);
        d0 = __builtin_amdgcn_mfma_f32_16x16x32_f16(Wf[1], Xh0, d0, 0, 0, 0);
        d0 = __builtin_amdgcn_mfma_f32_16x16x32_f16(Wf[4], Xh1, d0, 0, 0, 0);
        d0 = __builtin_amdgcn_mfma_f32_16x16x32_f16(Wf[4], Xl1, d0, 0, 0, 0);
        d0 = __builtin_amdgcn_mfma_f32_16x16x32_f16(Wf[5], Xh1, d0, 0, 0, 0);
        d1 = __builtin_amdgcn_mfma_f32_16x16x32_f16(Wf[2], Xh0, d1, 0, 0, 0);
        d1 = __builtin_amdgcn_mfma_f32_16x16x32_f16(Wf[2], Xl0, d1, 0, 0, 0);
        d1 = __builtin_amdgcn_mfma_f32_16x16x32_f16(Wf[3], Xh0, d1, 0, 0, 0);
        d1 = __builtin_amdgcn_mfma_f32_16x16x32_f16(Wf[6], Xh1, d1, 0, 0, 0);
        d1 = __builtin_amdgcn_mfma_f32_16x16x32_f16(Wf[6], Xl1, d1, 0, 0, 0);
        d1 = __builtin_amdgcn_mfma_f32_16x16x32_f16(Wf[7], Xh1, d1, 0, 0, 0);
        if (valid) {
            int sw = (cx & 7) << 4;
            char* pxb = f1t + ry * 4352 + cx * 128;
#pragma unroll
            for (int h = 0; h < 2; h++) {
                f32x4 d = h ? d1 : d0;
                half4 hq, lq;
#pragma unroll
                for (int j = 0; j < 4; j++) {
                    float v = d[j];
                    v = fmaxf(v, 0.2f * v);
                    v = ok ? v : 0.f;
                    _Float16 hv = (_Float16)v;
                    hq[j] = hv;
                    lq[j] = (_Float16)(v - (float)hv);
                }
                int q8 = (h * 4 + cg) * 8;
                *(half4*)(pxb + (q8 ^ sw)) = hq;
                *(half4*)(pxb + ((64 + q8) ^ sw)) = lq;
            }
        }
    }
    __syncthreads();

    // phase 3: conv2 via rolling-row f16x2 MFMA, operands swapped: D = W*X
    // lane: px = lane&15 (+wx*16), co = (lane>>4)*4 + j  -> direct store, no transpose
    int wx = wid & 1, wy = wid >> 1;
    f32x4 acc2[4];
#pragma unroll
    for (int r = 0; r < 4; r++) acc2[r] = binit;
#pragma unroll
    for (int iy = 0; iy < 6; iy++) {
        int f1row = wy * 4 + iy;
        half8 ah[3], al[3];
#pragma unroll
        for (int kx = 0; kx < 3; kx++) {
            int pxi = wx * 16 + m + kx;
            int base = f1row * 4352 + pxi * 128;
            int sw = (pxi & 7) << 4;
            ah[kx] = *(const half8*)(f1t + base + ((b * 16) ^ sw));
            al[kx] = *(const half8*)(f1t + base + ((64 + b * 16) ^ sw));
        }
#pragma unroll
        for (int kx = 0; kx < 3; kx++) {
#pragma unroll
            for (int ry = 0; ry < 4; ry++) {
                if (ry >= iy - 2 && ry <= iy) {
                    const int t = (iy - ry) * 3 + kx;
                    acc2[ry] = __builtin_amdgcn_mfma_f32_16x16x32_f16(Bh[t], ah[kx], acc2[ry], 0, 0, 0);
                    acc2[ry] = __builtin_amdgcn_mfma_f32_16x16x32_f16(Bl[t], ah[kx], acc2[ry], 0, 0, 0);
                    acc2[ry] = __builtin_amdgcn_mfma_f32_16x16x32_f16(Bh[t], al[kx], acc2[ry], 0, 0, 0);
                }
            }
        }
    }

    // epilogue: leaky -> pack f16 h/l -> direct store (lane owns px = bx+wx*16+m)
    int x0 = bx + wx * 16 + m;
    int y0 = by + wy * 4;
    int co_off = (b >> 1) * 8 + (b & 1) * 4;
#pragma unroll
    for (int ry = 0; ry < 4; ry++) {
        half4 hq, lq;
#pragma unroll
        for (int j = 0; j < 4; j++) {
            float v = acc2[ry][j];
            v = fmaxf(v, 0.2f * v);
            _Float16 hv = (_Float16)v;
            hq[j] = hv;
            lq[j] = (_Float16)(v - (float)hv);
        }
        size_t base = ((size_t)(y0 + ry) * W + x0) * 32;
        *(half4*)(f2n + base + co_off) = hq;
        *(half4*)(f2n + base + 16 + co_off) = lq;
    }
}

// ---------------- conv3: LDS-staged f16x2 MFMA, 32x8 tile, branch-free ----------------
__global__ __launch_bounds__(256) void conv3_mfma(const _Float16* __restrict__ f2n,
                                                  const _Float16* __restrict__ w3f,
                                                  const float* __restrict__ bias,
                                                  float* __restrict__ f3) {
    __shared__ __align__(16) char st[10 * 34 * 80];    // 27200 B
    int tid = threadIdx.x;
    int lane = tid & 63;
    int wid = tid >> 6;
    int bx = blockIdx.x * 32, by = blockIdx.y * 8;

    // stage: rows by-1..by+8, px bx-1..bx+32, 4 x 16B chunks per px
    // idx = (r*34 + p)*4 + c walked incrementally (step 256 = +1 row +30 px, c fixed)
    {
        int c0 = tid & 3;
        int rem = tid >> 2;                            // < 64
        int r = rem >= 34 ? 1 : 0, p = rem - r * 34;
        int idx = tid;
#pragma unroll
        for (int it = 0; it < 6; ++it) {
            if (idx < 1360) {
                int gy = by + r - 1, gx = bx + p - 1;
                half8 v = {0, 0, 0, 0, 0, 0, 0, 0};
                if ((unsigned)gy < H && (unsigned)gx < W)
                    v = *(const half8*)(f2n + ((size_t)gy * W + gx) * 32 + c0 * 8);
                *(half8*)(st + r * 2720 + p * 80 + c0 * 16) = v;
            }
            idx += 256;
            r += 1; p += 30; if (p >= 34) { p -= 34; r += 1; }
        }
    }

    half8 F[12];
#pragma unroll
    for (int t = 0; t < 12; t++)
        F[t] = *(const half8*)(w3f + (t * 64 + lane) * 8);
    int m = lane & 15, b = lane >> 4;
    int halfco = b & 1, kxp = b >> 1;
    int wx = wid & 1, wy = wid >> 1;
    float bc = (m < 8) ? bias[m] : 0.f;
    f32x4 acc[4];
#pragma unroll
    for (int r = 0; r < 4; r++) acc[r] = (f32x4){bc, bc, bc, bc};
    int pA = wx * 16 + m + kxp;                        // halo-local px for A (kx -1,0)
    int pB = wx * 16 + m + 2;                          // halo-local px for B (kx +1)
    __syncthreads();

#pragma unroll
    for (int iy = 0; iy < 6; iy++) {
        const char* rp = st + (wy * 4 + iy) * 2720;
        half8 ka_h = *(const half8*)(rp + pA * 80 + halfco * 16);
        half8 ka_l = *(const half8*)(rp + pA * 80 + halfco * 16 + 32);
        half8 kb_h = *(const half8*)(rp + pB * 80 + halfco * 16);
        half8 kb_l = *(const half8*)(rp + pB * 80 + halfco * 16 + 32);
#pragma unroll
        for (int ry = 0; ry < 4; ry++) {
            if (ry >= iy - 2 && ry <= iy) {
                const int ky = iy - ry;
                acc[ry] = __builtin_amdgcn_mfma_f32_16x16x32_f16(ka_h, F[ky * 4 + 0], acc[ry], 0, 0, 0);
                acc[ry] = __builtin_amdgcn_mfma_f32_16x16x32_f16(ka_h, F[ky * 4 + 1], acc[ry], 0, 0, 0);
                acc[ry] = __builtin_amdgcn_mfma_f32_16x16x32_f16(ka_l, F[ky * 4 + 0], acc[ry], 0, 0, 0);
                acc[ry] = __builtin_amdgcn_mfma_f32_16x16x32_f16(kb_h, F[ky * 4 + 2], acc[ry], 0, 0, 0);
                acc[ry] = __builtin_amdgcn_mfma_f32_16x16x32_f16(kb_h, F[ky * 4 + 3], acc[ry], 0, 0, 0);
                acc[ry] = __builtin_amdgcn_mfma_f32_16x16x32_f16(kb_l, F[ky * 4 + 2], acc[ry], 0, 0, 0);
            }
        }
    }

    if (m < 8) {
#pragma unroll
        for (int ry = 0; ry < 4; ry++) {
            int y = by + wy * 4 + ry;
            *(float4*)(f3 + (size_t)m * HW + (size_t)y * W + bx + wx * 16 + b * 4) =
                make_float4(acc[ry][0], acc[ry][1], acc[ry][2], acc[ry][3]);
        }
    }
}

// ---------------- stdfuse (fused v3): 8-channel std maps + fusion + threshold + sigmoid ----------------
__global__ __launch_bounds__(256) void stdfuse_fused(const float* __restrict__ f3all,
                                                     const float* __restrict__ fw,
                                                     const float* __restrict__ fb,
                                                     const float* __restrict__ stats,
                                                     float* __restrict__ out) {
    __shared__ __align__(16) float raw[46 * 50];
    __shared__ __align__(16) float hsq[3][46 * 76];
    __shared__ int rowOff[46];      // reflected gy * W (element offset)
    __shared__ int gxcol[46];       // reflected gx
    int tid = threadIdx.x;
    int xq = tid & 15, yp = tid >> 4;
    int bx = blockIdx.x * 32, by = blockIdx.y * 32;
    int batch = blockIdx.z;
    const float* f3 = f3all + (size_t)batch * 8 * HW;

    if (tid < 46) {
        int gy = by + tid - 7;
        gy = gy < 0 ? -gy : (gy > 1023 ? 2046 - gy : gy);
        rowOff[tid] = gy * W;
        int gx = bx + tid - 7;
        gx = gx < 0 ? -gx : (gx > 1023 ? 2046 - gx : gx);
        gxcol[tid] = gx;
    }
    __syncthreads();

    // per-thread staging task table (channel-invariant): 2116 = 8*256 + 68 tasks
    int goffB[9];   // global byte offset within a channel plane
    int laddB[9];   // LDS byte offset into raw
    const bool k8 = tid < 68;
#pragma unroll
    for (int k = 0; k < 9; k++) {
        int idx = tid + k * 256;
        int idc = idx < 2116 ? idx : 2115;
        int r = idc / 46, c = idc - r * 46;
        goffB[k] = (rowOff[r] + gxcol[c]) * 4;
        laddB[k] = (r * 50 + c) * 4;
    }

    float wwin[3] = {fw[0] * 0.125f, fw[1] * 0.125f, fw[2] * 0.125f};
    float part[4] = {0.f, 0.f, 0.f, 0.f};

    // prologue: load channel 0 into registers
    float stg[9];
    {
        const char* src = (const char*)f3;
#pragma unroll
        for (int k = 0; k < 8; k++) stg[k] = *(const float*)(src + goffB[k]);
        stg[8] = k8 ? *(const float*)(src + goffB[8]) : 0.f;
    }

    for (int z = 0; z < 8; z++) {
        // write staged registers to raw (safe: prior phase-2 raw reads ended at barrier B)
        char* rb = (char*)raw;
#pragma unroll
        for (int k = 0; k < 8; k++) *(float*)(rb + laddB[k]) = stg[k];
        if (k8) *(float*)(rb + laddB[8]) = stg[8];

        // T14: issue next channel's loads BEFORE the barrier; latency hides under phase 2+3
        if (z < 7) {
            const char* nsrc = (const char*)(f3 + (size_t)(z + 1) * HW);
#pragma unroll
            for (int k = 0; k < 8; k++) stg[k] = *(const float*)(nsrc + goffB[k]);
            if (k8) stg[8] = *(const float*)(nsrc + goffB[8]);
        }
        __syncthreads();   // A: raw ready; prior phase-3 hsq reads complete

        // phase 2: horizontal window sums (s, q) for A/B pixel pairs, all 46 rows
        for (int idx = tid; idx < 736; idx += 256) {
            int r = idx >> 4, xh = idx & 15;
            const float* rp = raw + r * 50 + 2 * xh;
            float v[16], w[16];
#pragma unroll
            for (int k = 0; k < 8; k++) {
                float2 p = *(const float2*)(rp + 2 * k);
                v[2 * k] = p.x; v[2 * k + 1] = p.y;
            }
#pragma unroll
            for (int k = 0; k < 16; k++) w[k] = v[k] * v[k];
            float ms = v[6] + v[7] + v[8] + v[9];
            float mq = w[6] + w[7] + w[8] + w[9];
            float sA5 = v[5] + ms, sB5 = ms + v[10];
            float qA5 = w[5] + mq, qB5 = mq + w[10];
            float sA9 = sA5 + v[3] + v[4] + v[10] + v[11];
            float sB9 = sB5 + v[4] + v[5] + v[11] + v[12];
            float qA9 = qA5 + w[3] + w[4] + w[10] + w[11];
            float qB9 = qB5 + w[4] + w[5] + w[11] + w[12];
            float sA15 = sA9 + v[0] + v[1] + v[2] + v[12] + v[13] + v[14];
            float sB15 = sB9 + v[1] + v[2] + v[3] + v[13] + v[14] + v[15];
            float qA15 = qA9 + w[0] + w[1] + w[2] + w[12] + w[13] + w[14];
            float qB15 = qB9 + w[1] + w[2] + w[3] + w[13] + w[14] + w[15];
            int base = r * 76 + 4 * xh;
            *(float4*)&hsq[0][base] = make_float4(sA5, qA5, sB5, qB5);
            *(float4*)&hsq[1][base] = make_float4(sA9, qA9, sB9, qB9);
            *(float4*)&hsq[2][base] = make_float4(sA15, qA15, sB15, qB15);
        }
        __syncthreads();   // B: hsq ready; all raw reads complete

        // phase 3: vertical sums (dual accumulators) + std finishing
#pragma unroll
        for (int wi = 0; wi < 3; wi++) {
            const int wlen = (wi == 0) ? 5 : ((wi == 1) ? 9 : 15);
            const int r0 = 2 * yp + 7 - (wlen >> 1);
            const float inv = 1.0f / (float)(wlen * wlen);
            const float ww = wwin[wi];
            const float* basep = &hsq[wi][4 * xq];
            float4 first = *(const float4*)(basep + r0 * 76);
            float4 e = first;
            float4 o = *(const float4*)(basep + (r0 + 1) * 76);
#pragma unroll
            for (int k = 2; k + 1 < wlen; k += 2) {
                float4 pe = *(const float4*)(basep + (r0 + k) * 76);
                float4 po = *(const float4*)(basep + (r0 + k + 1) * 76);
                e.x += pe.x; e.y += pe.y; e.z += pe.z; e.w += pe.w;
                o.x += po.x; o.y += po.y; o.z += po.z; o.w += po.w;
            }
            {   // last even row (wlen odd -> index wlen-1 is even)
                float4 pe = *(const float4*)(basep + (r0 + wlen - 1) * 76);
                e.x += pe.x; e.y += pe.y; e.z += pe.z; e.w += pe.w;
            }
            float4 accv = make_float4(e.x + o.x, e.y + o.y, e.z + o.z, e.w + o.w);
            float4 last = *(const float4*)(basep + (r0 + wlen) * 76);
            float sA1 = accv.x - first.x + last.x;
            float qA1 = accv.y - first.y + last.y;
            float sB1 = accv.z - first.z + last.z;
            float qB1 = accv.w - first.w + last.w;
            float mA0 = accv.x * inv, m2A0 = accv.y * inv;
            part[0] += ww * fast_sqrtf(fmaxf(m2A0 - mA0 * mA0, 0.f) + 1e-8f);
            float mB0 = accv.z * inv, m2B0 = accv.w * inv;
            part[1] += ww * fast_sqrtf(fmaxf(m2B0 - mB0 * mB0, 0.f) + 1e-8f);
            float mA1 = sA1 * inv, m2A1 = qA1 * inv;
            part[2] += ww * fast_sqrtf(fmaxf(m2A1 - mA1 * mA1, 0.f) + 1e-8f);
            float mB1 = sB1 * inv, m2B1 = qB1 * inv;
            part[3] += ww * fast_sqrtf(fmaxf(m2B1 - mB1 * mB1, 0.f) + 1e-8f);
        }
        // no barrier: next iter writes raw (disjoint from hsq); hsq rewritten only after next barrier A
    }

    // epilogue: fused value -> per-channel threshold + sigmoid, direct output write
    float fb0 = fb[0];
    int gy = by + 2 * yp, gx = bx + 2 * xq;
#pragma unroll
    for (int c = 0; c < 4; c++) {
        float lo = stats[(batch * 4 + c) * 2];
        float up = stats[(batch * 4 + c) * 2 + 1];
        float inv = 1.f / (up - lo);
        float v[4];
#pragma unroll
        for (int p = 0; p < 4; p++) {
            float ns = (part[p] + fb0 - lo) * inv;
            ns = fminf(fmaxf(ns, 0.f), 1.f);
            v[p] = 1.f / (1.f + fast_expf(3.f - 6.f * ns));
        }
        float* plane = out + ((size_t)(batch * 4 + c)) * HW;
        *(float2*)(plane + (size_t)gy * W + gx) = make_float2(v[0], v[1]);
        *(float2*)(plane + (size_t)(gy + 1) * W + gx) = make_float2(v[2], v[3]);
    }
}

extern "C" void kernel_launch(void* const* d_in, const int* in_sizes, int n_in,
                              void* d_out, int out_size, void* d_ws, size_t ws_size,
                              hipStream_t stream) {
    (void)in_sizes; (void)n_in; (void)out_size; (void)ws_size;
    const float* x = (const float*)d_in[0];
    const float* w1 = (const float*)d_in[1];
    const float* b1 = (const float*)d_in[2];
    const float* w2 = (const float*)d_in[3];
    const float* b2 = (const float*)d_in[4];
    const float* w3 = (const float*)d_in[5];
    const float* b3 = (const float*)d_in[6];
    const float* chw = (const float*)d_in[7];
    const float* fw = (const float*)d_in[8];
    const float* fb = (const float*)d_in[9];
    float* out = (float*)d_out;

    char* ws = (char*)d_ws;
    float* stats = (float*)ws;                         // 32 f
    double* part = (double*)(ws + 256);                // 1024 d, ends 8448
    _Float16* w1a = (_Float16*)(ws + 8448);            // 4096 f16, ends 16640
    _Float16* w3f = (_Float16*)(ws + 24832);           // 6144 f16, ends 37120
    _Float16* w2bh = (_Float16*)(ws + 37120);          // 4608 f16, ends 46336
    _Float16* w2bl = (_Float16*)(ws + 46336);          // 4608 f16, ends 55552
    float* f3all = (float*)(ws + 65536);               // 4 batches x 8 ch x HW f32 = 128 MB
    _Float16* f2n = (_Float16*)(ws + 134283264);       // 64 MB (reused per batch, L3-resident)

    stats_partial<<<512, 256, 0, stream>>>(x, part);
    stats_final_prep<<<1, 256, 0, stream>>>(part, chw, w1, w2, w3, stats, w1a, w3f, w2bh, w2bl);

    for (int b = 0; b < 4; b++) {
        const float* xb = x + (size_t)b * 4 * HW;
        conv12_mfma<<<dim3(32, 128), 256, 0, stream>>>(xb, w1a, b1, w2bh, w2bl, b2, f2n);
        conv3_mfma<<<dim3(32, 128), 256, 0, stream>>>(f2n, w3f, b3, f3all + (size_t)b * 8 * HW);
    }
    stdfuse_fused<<<dim3(32, 32, 4), 256, 0, stream>>>(f3all, fw, fb, stats, out);
}